// Round 8
// baseline (334.559 us; speedup 1.0000x reference)
//
#include <hip/hip_runtime.h>
#include <math.h>

#define B_   16
#define C_   512
#define C8_  64
#define HW_  4096
#define KW2_ 576   // C_ + C8_
#define EPS_ 1e-5f

typedef __attribute__((ext_vector_type(8))) short bf16x8;
typedef __attribute__((ext_vector_type(4))) float f32x4;

__device__ __forceinline__ unsigned short f2bf(float f) {
    union { float f; unsigned u; } v; v.f = f;
    unsigned r = (v.u + 0x7FFFu + ((v.u >> 16) & 1u)) >> 16;  // RNE
    return (unsigned short)r;
}

// 16-output FMA microtile: accv[i] += rowptr[i] * sv (fp32 path)
#define FMA16(accv, sv, rowptr) do {                                            \
    const float4* _w = (const float4*)(rowptr);                                 \
    float4 _w0 = _w[0], _w1 = _w[1], _w2 = _w[2], _w3 = _w[3];                  \
    float _s = (sv);                                                            \
    accv[0]  += _w0.x*_s; accv[1]  += _w0.y*_s; accv[2]  += _w0.z*_s; accv[3]  += _w0.w*_s; \
    accv[4]  += _w1.x*_s; accv[5]  += _w1.y*_s; accv[6]  += _w1.z*_s; accv[7]  += _w1.w*_s; \
    accv[8]  += _w2.x*_s; accv[9]  += _w2.y*_s; accv[10] += _w2.z*_s; accv[11] += _w2.w*_s; \
    accv[12] += _w3.x*_s; accv[13] += _w3.y*_s; accv[14] += _w3.z*_s; accv[15] += _w3.w*_s; \
} while (0)

// ---------------------------------------------------------------------------
// A: fused proj_key + partial energy (fp32). grid (64, B), block (64,4).
// One 64-wide n-chunk per block; LDS tiles aliased (33 KB) -> 4 blocks/CU.
// epart[b][ch][q][k], ch in [0,64).
// ---------------------------------------------------------------------------
__global__ __launch_bounds__(256) void k_key_energy(
        const float* __restrict__ x, const float* __restrict__ key_w,
        const float* __restrict__ key_b, const float* __restrict__ att,
        float* __restrict__ epart) {
    __shared__ __align__(16) float sA[64][65];   // x tile [c][n]  -> key tile [k][n]
    __shared__ __align__(16) float sW[64][68];   // key_w [c][k]   -> att tile [n][q]
    const int tx = threadIdx.x, ty = threadIdx.y;
    const int ch = blockIdx.x, b = blockIdx.y;
    const int nb = ch * 64;

    float kacc[16];
    #pragma unroll
    for (int i = 0; i < 16; ++i) kacc[i] = 0.f;

    for (int cc = 0; cc < 8; ++cc) {
        const int c0 = cc * 64;
        #pragma unroll
        for (int i = 0; i < 16; ++i) {
            const int r = ty * 16 + i;
            sA[r][tx] = x[((size_t)b * C_ + c0 + r) * HW_ + nb + tx];
            sW[tx][r] = key_w[(size_t)r * C_ + c0 + tx];
        }
        __syncthreads();
        #pragma unroll 4
        for (int jj = 0; jj < 64; ++jj)
            FMA16(kacc, sA[jj][tx], &sW[jj][ty * 16]);  // kacc[i]: k=ty*16+i, n=tx
        __syncthreads();   // also guards the aliased overwrite below
    }
    // reuse sA as key tile [k][n], sW as att^T tile [n][q]
    #pragma unroll
    for (int i = 0; i < 16; ++i) {
        const int r = ty * 16 + i;
        sA[r][tx] = kacc[i] + key_b[r];
        sW[tx][r] = att[((size_t)b * C8_ + r) * HW_ + nb + tx];
    }
    __syncthreads();

    float eacc[16];
    #pragma unroll
    for (int i = 0; i < 16; ++i) eacc[i] = 0.f;
    #pragma unroll 4
    for (int nn = 0; nn < 64; ++nn)
        FMA16(eacc, sA[tx][nn], &sW[nn][ty * 16]);  // eacc[j]: q=ty*16+j, k=tx

    #pragma unroll
    for (int j = 0; j < 16; ++j) {
        const int q = ty * 16 + j;
        epart[((size_t)(b * 64 + ch) * 64 + q) * 64 + tx] = eacc[j];
    }
}

// ---------------------------------------------------------------------------
// B: reduce 64 partials -> softmax(q) -> M[b][o][q] = s1[o]*sum_k c1_w[o,k]*attn[k,q]
// grid (B), block (64,4).
// ---------------------------------------------------------------------------
__global__ __launch_bounds__(256) void k_softmax_M(
        const float* __restrict__ epart, const float* __restrict__ c1_w,
        const float* __restrict__ c1_gamma, const float* __restrict__ c1_var,
        float* __restrict__ M) {
    __shared__ __align__(16) float eT[64][65];
    __shared__ __align__(16) float attnS[64][65];
    __shared__ __align__(16) float c1T[64][68];
    const int tx = threadIdx.x, ty = threadIdx.y;
    const int t = ty * 64 + tx;
    const int b = blockIdx.x;

    for (int idx = t; idx < 4096; idx += 256) {
        float s = 0.f;
        #pragma unroll 8
        for (int ch = 0; ch < 64; ++ch)
            s += epart[(size_t)(b * 64 + ch) * 4096 + idx];
        eT[idx >> 6][idx & 63] = s;
    }
    #pragma unroll
    for (int i = 0; i < 16; ++i) {
        const int oo = ty * 16 + i;
        c1T[tx][oo] = c1_w[oo * 64 + tx];
    }
    __syncthreads();

    if (t < 64) {
        const int k = t;
        float m = -1e30f;
        for (int q = 0; q < 64; ++q) m = fmaxf(m, eT[q][k]);
        float s = 0.f;
        for (int q = 0; q < 64; ++q) {
            const float p = __expf(eT[q][k] - m);
            attnS[k][q] = p;
            s += p;
        }
        const float inv = 1.f / s;
        for (int q = 0; q < 64; ++q) attnS[k][q] *= inv;
    }
    __syncthreads();

    float acc[16];
    #pragma unroll
    for (int i = 0; i < 16; ++i) acc[i] = 0.f;
    #pragma unroll 4
    for (int k = 0; k < 64; ++k)
        FMA16(acc, attnS[k][tx], &c1T[k][ty * 16]);
    #pragma unroll
    for (int i = 0; i < 16; ++i) {
        const int o = ty * 16 + i;
        const float s1 = c1_gamma[o] * rsqrtf(c1_var[o] + EPS_);
        M[((size_t)b * 64 + o) * 64 + tx] = s1 * acc[i];
    }
}

// ---------------------------------------------------------------------------
// T1: transpose-convert x -> actT[b][n][C8_+c] bf16. grid (64, 8, B), 256 thr.
// ---------------------------------------------------------------------------
__global__ __launch_bounds__(256) void k_xT(
        const float* __restrict__ x, unsigned short* __restrict__ actT) {
    __shared__ float S[64][65];
    const int t = threadIdx.x;
    const int tx = t & 63, ty = t >> 6;
    const int n0 = blockIdx.x * 64, c0 = blockIdx.y * 64, b = blockIdx.z;
    #pragma unroll
    for (int i = 0; i < 16; ++i) {
        const int r = ty * 16 + i;
        S[r][tx] = x[((size_t)(b * C_ + c0 + r)) * HW_ + n0 + tx];
    }
    __syncthreads();
    const int nl = t >> 2, seg = t & 3;
    unsigned short tmp[16];
    #pragma unroll
    for (int j = 0; j < 16; ++j) tmp[j] = f2bf(S[seg * 16 + j][nl]);
    unsigned short* dst = actT + ((size_t)(b * HW_ + n0 + nl)) * KW2_ + C8_ + c0 + seg * 16;
    *(bf16x8*)(dst)     = *(const bf16x8*)&tmp[0];
    *(bf16x8*)(dst + 8) = *(const bf16x8*)&tmp[8];
}

// ---------------------------------------------------------------------------
// T2: t[j,n] = relu(sum_q M[b,j,q]*att[b,q,n] + bias1[j]) -> actT[b][n][j] bf16
// grid (64, B), 256 thr.
// ---------------------------------------------------------------------------
__global__ __launch_bounds__(256) void k_t_bf(
        const float* __restrict__ att, const float* __restrict__ Mw,
        const float* __restrict__ c1_b, const float* __restrict__ c1_gamma,
        const float* __restrict__ c1_beta, const float* __restrict__ c1_mean,
        const float* __restrict__ c1_var, unsigned short* __restrict__ actT) {
    __shared__ __align__(16) float attS[64][65];
    __shared__ __align__(16) float MT[64][68];
    __shared__ float tS[64][65];
    const int t = threadIdx.x;
    const int tx = t & 63, ty = t >> 6;
    const int n0 = blockIdx.x * 64, b = blockIdx.y;

    #pragma unroll
    for (int i = 0; i < 16; ++i) {
        const int r = ty * 16 + i;
        attS[r][tx] = att[((size_t)b * C8_ + r) * HW_ + n0 + tx];
        MT[tx][r]   = Mw[((size_t)b * 64 + r) * 64 + tx];
    }
    __syncthreads();
    float acc[16];
    #pragma unroll
    for (int i = 0; i < 16; ++i) acc[i] = 0.f;
    #pragma unroll 4
    for (int q = 0; q < 64; ++q)
        FMA16(acc, attS[q][tx], &MT[q][ty * 16]);
    #pragma unroll
    for (int i = 0; i < 16; ++i) {
        const int j = ty * 16 + i;
        const float s1 = c1_gamma[j] * rsqrtf(c1_var[j] + EPS_);
        const float bias = s1 * c1_b[j] + c1_beta[j] - c1_mean[j] * s1;
        tS[j][tx] = fmaxf(acc[i] + bias, 0.f);
    }
    __syncthreads();
    const int nl = t >> 2, seg = t & 3;
    unsigned short tmp[16];
    #pragma unroll
    for (int j = 0; j < 16; ++j) tmp[j] = f2bf(tS[seg * 16 + j][nl]);
    unsigned short* dst = actT + ((size_t)(b * HW_ + n0 + nl)) * KW2_ + seg * 16;
    *(bf16x8*)(dst)     = *(const bf16x8*)&tmp[0];
    *(bf16x8*)(dst + 8) = *(const bf16x8*)&tmp[8];
}

// ---------------------------------------------------------------------------
// G: conv2 as bf16 MFMA GEMM. out[b,o,n] = relu((s2*W)·act + bias2)
// Block 128x128, 4 waves (2x2), wave tile 64x64 (4x4 of 16x16x32 MFMA).
// LDS: XOR-swizzled 16B blocks (kb ^ (row&7)), row stride 128B.
// grid (32, 4, B), 256 thr.
// ---------------------------------------------------------------------------
__global__ __launch_bounds__(256) void k_conv2_mfma(
        const unsigned short* __restrict__ actT, const float* __restrict__ c2_w,
        const float* __restrict__ c2_b, const float* __restrict__ c2_gamma,
        const float* __restrict__ c2_beta, const float* __restrict__ c2_mean,
        const float* __restrict__ c2_var, float* __restrict__ out) {
    __shared__ __align__(16) unsigned short At[128 * 64];
    __shared__ __align__(16) unsigned short Bt[128 * 64];
    const int t = threadIdx.x;
    const int lane = t & 63, wave = t >> 6;
    const int wr = wave >> 1, wc = wave & 1;
    const int n0 = blockIdx.x * 128, o0 = blockIdx.y * 128, b = blockIdx.z;

    const int srow = t >> 1, shalf = t & 1;
    const int oA = o0 + srow;
    const float s2A = c2_gamma[oA] * rsqrtf(c2_var[oA] + EPS_);

    f32x4 acc[4][4];
    #pragma unroll
    for (int m = 0; m < 4; ++m)
        #pragma unroll
        for (int n = 0; n < 4; ++n) acc[m][n] = (f32x4){0.f, 0.f, 0.f, 0.f};

    for (int ks = 0; ks < 9; ++ks) {
        const int k0 = ks * 64;
        {   // stage A: weights fp32 -> bf16, s2-scaled
            const float4* src = (const float4*)(c2_w + (size_t)oA * KW2_ + k0 + shalf * 32);
            unsigned short tmp[32];
            #pragma unroll
            for (int v = 0; v < 8; ++v) {
                float4 f = src[v];
                tmp[v * 4 + 0] = f2bf(f.x * s2A);
                tmp[v * 4 + 1] = f2bf(f.y * s2A);
                tmp[v * 4 + 2] = f2bf(f.z * s2A);
                tmp[v * 4 + 3] = f2bf(f.w * s2A);
            }
            #pragma unroll
            for (int v = 0; v < 4; ++v) {
                const int kb = shalf * 4 + v;
                *(bf16x8*)&At[srow * 64 + ((kb ^ (srow & 7)) << 3)] =
                    *(const bf16x8*)&tmp[v * 8];
            }
        }
        {   // stage B: actT bf16 direct copy
            const unsigned short* src =
                actT + ((size_t)(b * HW_ + n0 + srow)) * KW2_ + k0 + shalf * 32;
            #pragma unroll
            for (int v = 0; v < 4; ++v) {
                const int kb = shalf * 4 + v;
                *(bf16x8*)&Bt[srow * 64 + ((kb ^ (srow & 7)) << 3)] =
                    *(const bf16x8*)(src + v * 8);
            }
        }
        __syncthreads();
        #pragma unroll
        for (int kk = 0; kk < 2; ++kk) {
            const int g = lane >> 4, a7 = lane & 7, r15 = lane & 15;
            const int kb = kk * 4 + g;
            bf16x8 af[4], bfv[4];
            #pragma unroll
            for (int m = 0; m < 4; ++m) {
                const int row = wr * 64 + m * 16 + r15;
                af[m] = *(const bf16x8*)&At[row * 64 + ((kb ^ a7) << 3)];
            }
            #pragma unroll
            for (int n = 0; n < 4; ++n) {
                const int row = wc * 64 + n * 16 + r15;
                bfv[n] = *(const bf16x8*)&Bt[row * 64 + ((kb ^ a7) << 3)];
            }
            #pragma unroll
            for (int m = 0; m < 4; ++m)
                #pragma unroll
                for (int n = 0; n < 4; ++n)
                    acc[m][n] = __builtin_amdgcn_mfma_f32_16x16x32_bf16(
                        af[m], bfv[n], acc[m][n], 0, 0, 0);
        }
        __syncthreads();
    }
    #pragma unroll
    for (int m = 0; m < 4; ++m) {
        #pragma unroll
        for (int r = 0; r < 4; ++r) {
            const int o = o0 + wr * 64 + m * 16 + (lane >> 4) * 4 + r;
            const float s2 = c2_gamma[o] * rsqrtf(c2_var[o] + EPS_);
            const float bias = s2 * (c2_b[o] - c2_mean[o]) + c2_beta[o];
            float* orow = out + ((size_t)(b * C_ + o)) * HW_ + n0 + wc * 64 + (lane & 15);
            #pragma unroll
            for (int n = 0; n < 4; ++n)
                orow[n * 16] = fmaxf(acc[m][n][r] + bias, 0.f);
        }
    }
}

// ---------------------------------------------------------------------------
// Fallback (proven fp32 path): fused t-recompute + conv2 in fp32 VALU.
// ---------------------------------------------------------------------------
__global__ __launch_bounds__(256) void k_fused_out(
        const float* __restrict__ att, const float* __restrict__ Mw,
        const float* __restrict__ c1_b, const float* __restrict__ c1_gamma,
        const float* __restrict__ c1_beta, const float* __restrict__ c1_mean,
        const float* __restrict__ c1_var,
        const float* __restrict__ x, const float* __restrict__ c2_w,
        const float* __restrict__ c2_b, const float* __restrict__ c2_gamma,
        const float* __restrict__ c2_beta, const float* __restrict__ c2_mean,
        const float* __restrict__ c2_var, float* __restrict__ out) {
    __shared__ __align__(16) float sA[64][65];
    __shared__ __align__(16) float sW[64][68];
    __shared__ __align__(16) float tS[64][65];
    const int tx = threadIdx.x, ty = threadIdx.y;
    const int n0 = blockIdx.x * 64, o0 = blockIdx.y * 64, b = blockIdx.z;

    #pragma unroll
    for (int i = 0; i < 16; ++i) {
        const int r = ty * 16 + i;
        sA[r][tx] = att[((size_t)b * C8_ + r) * HW_ + n0 + tx];
        sW[tx][r] = Mw[((size_t)b * 64 + r) * 64 + tx];
    }
    __syncthreads();
    float acc[16];
    #pragma unroll
    for (int i = 0; i < 16; ++i) acc[i] = 0.f;
    #pragma unroll 4
    for (int q = 0; q < 64; ++q)
        FMA16(acc, sA[q][tx], &sW[q][ty * 16]);
    #pragma unroll
    for (int i = 0; i < 16; ++i) {
        const int j = ty * 16 + i;
        const float s1 = c1_gamma[j] * rsqrtf(c1_var[j] + EPS_);
        const float bias = s1 * c1_b[j] + c1_beta[j] - c1_mean[j] * s1;
        tS[j][tx] = fmaxf(acc[i] + bias, 0.f);
    }
    __syncthreads();

    #pragma unroll
    for (int i = 0; i < 16; ++i) acc[i] = 0.f;
    for (int cch = 0; cch < 9; ++cch) {
        #pragma unroll
        for (int i = 0; i < 16; ++i) {
            const int r = ty * 16 + i;
            sW[tx][r] = c2_w[(size_t)(o0 + r) * KW2_ + cch * 64 + tx];
            if (cch > 0)
                sA[r][tx] = x[((size_t)b * C_ + (cch - 1) * 64 + r) * HW_ + n0 + tx];
        }
        __syncthreads();
        const float (*src)[65] = (cch == 0) ? tS : sA;
        #pragma unroll 4
        for (int jj = 0; jj < 64; ++jj)
            FMA16(acc, src[jj][tx], &sW[jj][ty * 16]);
        __syncthreads();
    }
    #pragma unroll
    for (int i = 0; i < 16; ++i) {
        const int o = o0 + ty * 16 + i;
        const float s2 = c2_gamma[o] * rsqrtf(c2_var[o] + EPS_);
        const float v = (acc[i] + c2_b[o]) * s2 + c2_beta[o] - c2_mean[o] * s2;
        out[((size_t)b * C_ + o) * HW_ + n0 + tx] = fmaxf(v, 0.f);
    }
}

extern "C" void kernel_launch(void* const* d_in, const int* in_sizes, int n_in,
                              void* d_out, int out_size, void* d_ws, size_t ws_size,
                              hipStream_t stream) {
    const float* x        = (const float*)d_in[0];
    const float* att      = (const float*)d_in[1];
    const float* key_w    = (const float*)d_in[2];
    const float* key_b    = (const float*)d_in[3];
    const float* c1_w     = (const float*)d_in[4];
    const float* c1_b     = (const float*)d_in[5];
    const float* c1_gamma = (const float*)d_in[6];
    const float* c1_beta  = (const float*)d_in[7];
    const float* c1_mean  = (const float*)d_in[8];
    const float* c1_var   = (const float*)d_in[9];
    const float* c2_w     = (const float*)d_in[10];
    const float* c2_b     = (const float*)d_in[11];
    const float* c2_gamma = (const float*)d_in[12];
    const float* c2_beta  = (const float*)d_in[13];
    const float* c2_mean  = (const float*)d_in[14];
    const float* c2_var   = (const float*)d_in[15];
    float* out = (float*)d_out;

    // ws layout: M (256 KB) | actT (B*HW*576 bf16 = 75.5 MB)
    float* M = (float*)d_ws;
    unsigned short* actT = (unsigned short*)((char*)d_ws + 262144);
    const size_t ws_needed = 262144 + (size_t)B_ * HW_ * KW2_ * 2;

    // epart borrows the head of d_out (16.8 MB < 134 MB); consumed by
    // k_softmax_M before anything writes out (stream-ordered).
    float* epart = out;

    dim3 blk(64, 4);
    k_key_energy<<<dim3(64, B_), blk, 0, stream>>>(x, key_w, key_b, att, epart);
    k_softmax_M <<<dim3(B_),     blk, 0, stream>>>(epart, c1_w, c1_gamma, c1_var, M);

    if (ws_size >= ws_needed) {
        k_xT        <<<dim3(64, 8, B_), 256, 0, stream>>>(x, actT);
        k_t_bf      <<<dim3(64, B_),    256, 0, stream>>>(
            att, M, c1_b, c1_gamma, c1_beta, c1_mean, c1_var, actT);
        k_conv2_mfma<<<dim3(32, 4, B_), 256, 0, stream>>>(
            actT, c2_w, c2_b, c2_gamma, c2_beta, c2_mean, c2_var, out);
    } else {
        k_fused_out<<<dim3(HW_ / 64, C_ / 64, B_), blk, 0, stream>>>(
            att, M, c1_b, c1_gamma, c1_beta, c1_mean, c1_var,
            x, c2_w, c2_b, c2_gamma, c2_beta, c2_mean, c2_var, out);
    }
}

// Round 17
// 291.380 us; speedup vs baseline: 1.1482x; 1.1482x over previous
//
#include <hip/hip_runtime.h>
#include <math.h>

#define B_   16
#define C_   512
#define C8_  64
#define HW_  4096
#define KW2_ 576   // C_ + C8_
#define EPS_ 1e-5f

typedef __attribute__((ext_vector_type(8))) short bf16x8;
typedef __attribute__((ext_vector_type(4))) float f32x4;

__device__ __forceinline__ unsigned short f2bf(float f) {
    union { float f; unsigned u; } v; v.f = f;
    unsigned r = (v.u + 0x7FFFu + ((v.u >> 16) & 1u)) >> 16;  // RNE
    return (unsigned short)r;
}

// 16-output FMA microtile: accv[i] += rowptr[i] * sv (fp32 path)
#define FMA16(accv, sv, rowptr) do {                                            \
    const float4* _w = (const float4*)(rowptr);                                 \
    float4 _w0 = _w[0], _w1 = _w[1], _w2 = _w[2], _w3 = _w[3];                  \
    float _s = (sv);                                                            \
    accv[0]  += _w0.x*_s; accv[1]  += _w0.y*_s; accv[2]  += _w0.z*_s; accv[3]  += _w0.w*_s; \
    accv[4]  += _w1.x*_s; accv[5]  += _w1.y*_s; accv[6]  += _w1.z*_s; accv[7]  += _w1.w*_s; \
    accv[8]  += _w2.x*_s; accv[9]  += _w2.y*_s; accv[10] += _w2.z*_s; accv[11] += _w2.w*_s; \
    accv[12] += _w3.x*_s; accv[13] += _w3.y*_s; accv[14] += _w3.z*_s; accv[15] += _w3.w*_s; \
} while (0)

// ---------------------------------------------------------------------------
// G kernel: epart[b][nc][c][q] = sum_{n in 512-chunk} x[b,c,n]*att[b,q,n]
// bf16 MFMA, both operands n-contiguous in global (transpose-free).
// Block: 128c x 64q, 4 waves (2x2), wave tile 64c x 32q. grid (8, 4, B).
// ---------------------------------------------------------------------------
__global__ __launch_bounds__(256) void k_G(
        const float* __restrict__ x, const float* __restrict__ att,
        float* __restrict__ epart) {
    __shared__ __align__(16) unsigned short Ax[128 * 64]; // x tile [c][n] swz
    __shared__ __align__(16) unsigned short Bq[64 * 64];  // att tile [q][n] swz
    const int t = threadIdx.x;
    const int lane = t & 63, wave = t >> 6;
    const int wr = wave >> 1, wc = wave & 1;
    const int nc = blockIdx.x, c0 = blockIdx.y * 128, b = blockIdx.z;

    f32x4 acc[4][2];
    #pragma unroll
    for (int m = 0; m < 4; ++m)
        #pragma unroll
        for (int n = 0; n < 2; ++n) acc[m][n] = (f32x4){0.f, 0.f, 0.f, 0.f};

    for (int ns = 0; ns < 8; ++ns) {
        const int nb = nc * 512 + ns * 64;
        {   // stage A: x rows (c), 128 rows x 64 n, fp32 -> bf16
            const int row = t >> 1, half = t & 1;
            const float4* src = (const float4*)(x + ((size_t)b * C_ + c0 + row) * HW_ + nb + half * 32);
            unsigned short tmp[32];
            #pragma unroll
            for (int v = 0; v < 8; ++v) {
                float4 f = src[v];
                tmp[v * 4 + 0] = f2bf(f.x); tmp[v * 4 + 1] = f2bf(f.y);
                tmp[v * 4 + 2] = f2bf(f.z); tmp[v * 4 + 3] = f2bf(f.w);
            }
            #pragma unroll
            for (int v = 0; v < 4; ++v) {
                const int kb = half * 4 + v;
                *(bf16x8*)&Ax[row * 64 + ((kb ^ (row & 7)) << 3)] =
                    *(const bf16x8*)&tmp[v * 8];
            }
        }
        {   // stage B: att rows (q), 64 rows x 64 n, fp32 -> bf16
            const int row = t >> 2, qt = t & 3;
            const float4* src = (const float4*)(att + ((size_t)b * C8_ + row) * HW_ + nb + qt * 16);
            unsigned short tmp[16];
            #pragma unroll
            for (int v = 0; v < 4; ++v) {
                float4 f = src[v];
                tmp[v * 4 + 0] = f2bf(f.x); tmp[v * 4 + 1] = f2bf(f.y);
                tmp[v * 4 + 2] = f2bf(f.z); tmp[v * 4 + 3] = f2bf(f.w);
            }
            #pragma unroll
            for (int v = 0; v < 2; ++v) {
                const int kb = qt * 2 + v;
                *(bf16x8*)&Bq[row * 64 + ((kb ^ (row & 7)) << 3)] =
                    *(const bf16x8*)&tmp[v * 8];
            }
        }
        __syncthreads();
        #pragma unroll
        for (int kk = 0; kk < 2; ++kk) {
            const int g = lane >> 4, a7 = lane & 7, r15 = lane & 15;
            const int kb = kk * 4 + g;
            bf16x8 af[4], bfv[2];
            #pragma unroll
            for (int m = 0; m < 4; ++m) {
                const int row = wr * 64 + m * 16 + r15;
                af[m] = *(const bf16x8*)&Ax[row * 64 + ((kb ^ a7) << 3)];
            }
            #pragma unroll
            for (int n = 0; n < 2; ++n) {
                const int row = wc * 32 + n * 16 + r15;
                bfv[n] = *(const bf16x8*)&Bq[row * 64 + ((kb ^ a7) << 3)];
            }
            #pragma unroll
            for (int m = 0; m < 4; ++m)
                #pragma unroll
                for (int n = 0; n < 2; ++n)
                    acc[m][n] = __builtin_amdgcn_mfma_f32_16x16x32_bf16(
                        af[m], bfv[n], acc[m][n], 0, 0, 0);
        }
        __syncthreads();
    }
    // D: row=(lane>>4)*4+i -> c, col=lane&15 -> q
    #pragma unroll
    for (int m = 0; m < 4; ++m) {
        #pragma unroll
        for (int i = 0; i < 4; ++i) {
            const int c = c0 + wr * 64 + m * 16 + (lane >> 4) * 4 + i;
            #pragma unroll
            for (int n = 0; n < 2; ++n) {
                const int q = wc * 32 + n * 16 + (lane & 15);
                epart[((size_t)(b * 8 + nc) * 512 + c) * 64 + q] = acc[m][n][i];
            }
        }
    }
}

// ---------------------------------------------------------------------------
// Reduce 8 n-chunk partials -> G[b][c][q]. grid (32, B), 256 thr.
// ---------------------------------------------------------------------------
__global__ __launch_bounds__(256) void k_reduceG(
        const float* __restrict__ epart, float* __restrict__ G) {
    const int idx4 = blockIdx.x * 256 + threadIdx.x;  // 0..8191 float4s per batch
    const int b = blockIdx.y;
    const float4* e4 = (const float4*)epart;
    float4 s = e4[((size_t)b * 8 + 0) * 8192 + idx4];
    #pragma unroll
    for (int nc = 1; nc < 8; ++nc) {
        float4 v = e4[((size_t)b * 8 + nc) * 8192 + idx4];
        s.x += v.x; s.y += v.y; s.z += v.z; s.w += v.w;
    }
    ((float4*)G)[(size_t)b * 8192 + idx4] = s;
}

// ---------------------------------------------------------------------------
// energy = key_w@G + key_b*S; softmax over q; M = s1 (.) (c1_w @ attn).
// grid (B), block (64,4).
// ---------------------------------------------------------------------------
__global__ __launch_bounds__(256) void k_energy_softmax_M(
        const float* __restrict__ G, const float* __restrict__ att,
        const float* __restrict__ key_w, const float* __restrict__ key_b,
        const float* __restrict__ c1_w, const float* __restrict__ c1_gamma,
        const float* __restrict__ c1_var, float* __restrict__ M) {
    __shared__ __align__(16) float bufA[64][65];  // kwS[k][c] -> attnS[k][q]
    __shared__ __align__(16) float bufB[64][68];  // GT[c][q]  -> c1T[k][o]
    __shared__ __align__(16) float eT[64][65];    // S-scratch -> energy [q][k]
    __shared__ float Ssh[64];
    const int tx = threadIdx.x, ty = threadIdx.y;
    const int t = ty * 64 + tx;
    const int b = blockIdx.x;

    // S[q] = sum_n att[b,q,n]
    {
        const int q = t & 63, part = t >> 6;
        const float4* a4 = (const float4*)(att + ((size_t)b * C8_ + q) * HW_) + part * 256;
        float s = 0.f;
        for (int i = 0; i < 256; ++i) { float4 v = a4[i]; s += v.x + v.y + v.z + v.w; }
        eT[part][q] = s;
    }
    __syncthreads();
    if (t < 64) Ssh[t] = eT[0][t] + eT[1][t] + eT[2][t] + eT[3][t];

    // energy accumulation: eacc[j]: k=tx, q=ty*16+j
    float eacc[16];
    #pragma unroll
    for (int i = 0; i < 16; ++i) eacc[i] = 0.f;
    for (int cc8 = 0; cc8 < 8; ++cc8) {
        const int c0 = cc8 * 64;
        #pragma unroll
        for (int i = 0; i < 16; ++i) {
            const int r = ty * 16 + i;
            bufA[r][tx] = key_w[(size_t)r * C_ + c0 + tx];          // kwS[k][c]
            bufB[r][tx] = G[((size_t)b * C_ + c0 + r) * 64 + tx];   // GT[c][q]
        }
        __syncthreads();
        #pragma unroll 4
        for (int cl = 0; cl < 64; ++cl)
            FMA16(eacc, bufA[tx][cl], &bufB[cl][ty * 16]);
        __syncthreads();
    }
    // store energy as eT[q][k]; load c1T into bufB
    #pragma unroll
    for (int j = 0; j < 16; ++j) {
        const int q = ty * 16 + j;
        eT[q][tx] = eacc[j] + key_b[tx] * Ssh[q];
    }
    #pragma unroll
    for (int i = 0; i < 16; ++i) {
        const int oo = ty * 16 + i;
        bufB[tx][oo] = c1_w[oo * 64 + tx];   // c1T[k][o]
    }
    __syncthreads();

    if (t < 64) {    // softmax over q per k-row -> attnS in bufA[k][q]
        const int k = t;
        float m = -1e30f;
        for (int q = 0; q < 64; ++q) m = fmaxf(m, eT[q][k]);
        float s = 0.f;
        for (int q = 0; q < 64; ++q) {
            const float p = __expf(eT[q][k] - m);
            bufA[k][q] = p;
            s += p;
        }
        const float inv = 1.f / s;
        for (int q = 0; q < 64; ++q) bufA[k][q] *= inv;
    }
    __syncthreads();

    float acc[16];
    #pragma unroll
    for (int i = 0; i < 16; ++i) acc[i] = 0.f;
    #pragma unroll 4
    for (int k = 0; k < 64; ++k)
        FMA16(acc, bufA[k][tx], &bufB[k][ty * 16]);   // acc[i]: o=ty*16+i, q=tx
    #pragma unroll
    for (int i = 0; i < 16; ++i) {
        const int o = ty * 16 + i;
        const float s1 = c1_gamma[o] * rsqrtf(c1_var[o] + EPS_);
        M[((size_t)b * 64 + o) * 64 + tx] = s1 * acc[i];
    }
}

// ---------------------------------------------------------------------------
// T1: transpose-convert x -> actT[b][n][C8_+c] bf16. grid (64, 8, B), 256 thr.
// ---------------------------------------------------------------------------
__global__ __launch_bounds__(256) void k_xT(
        const float* __restrict__ x, unsigned short* __restrict__ actT) {
    __shared__ float S[64][65];
    const int t = threadIdx.x;
    const int tx = t & 63, ty = t >> 6;
    const int n0 = blockIdx.x * 64, c0 = blockIdx.y * 64, b = blockIdx.z;
    #pragma unroll
    for (int i = 0; i < 16; ++i) {
        const int r = ty * 16 + i;
        S[r][tx] = x[((size_t)(b * C_ + c0 + r)) * HW_ + n0 + tx];
    }
    __syncthreads();
    const int nl = t >> 2, seg = t & 3;
    unsigned short tmp[16];
    #pragma unroll
    for (int j = 0; j < 16; ++j) tmp[j] = f2bf(S[seg * 16 + j][nl]);
    unsigned short* dst = actT + ((size_t)(b * HW_ + n0 + nl)) * KW2_ + C8_ + c0 + seg * 16;
    *(bf16x8*)(dst)     = *(const bf16x8*)&tmp[0];
    *(bf16x8*)(dst + 8) = *(const bf16x8*)&tmp[8];
}

// ---------------------------------------------------------------------------
// T2: t[j,n] = relu(sum_q M[b,j,q]*att[b,q,n] + bias1[j]) -> actT[b][n][j] bf16
// grid (64, B), 256 thr.
// ---------------------------------------------------------------------------
__global__ __launch_bounds__(256) void k_t_bf(
        const float* __restrict__ att, const float* __restrict__ Mw,
        const float* __restrict__ c1_b, const float* __restrict__ c1_gamma,
        const float* __restrict__ c1_beta, const float* __restrict__ c1_mean,
        const float* __restrict__ c1_var, unsigned short* __restrict__ actT) {
    __shared__ __align__(16) float attS[64][65];
    __shared__ __align__(16) float MT[64][68];
    __shared__ float tS[64][65];
    const int t = threadIdx.x;
    const int tx = t & 63, ty = t >> 6;
    const int n0 = blockIdx.x * 64, b = blockIdx.y;

    #pragma unroll
    for (int i = 0; i < 16; ++i) {
        const int r = ty * 16 + i;
        attS[r][tx] = att[((size_t)b * C8_ + r) * HW_ + n0 + tx];
        MT[tx][r]   = Mw[((size_t)b * 64 + r) * 64 + tx];
    }
    __syncthreads();
    float acc[16];
    #pragma unroll
    for (int i = 0; i < 16; ++i) acc[i] = 0.f;
    #pragma unroll 4
    for (int q = 0; q < 64; ++q)
        FMA16(acc, attS[q][tx], &MT[q][ty * 16]);
    #pragma unroll
    for (int i = 0; i < 16; ++i) {
        const int j = ty * 16 + i;
        const float s1 = c1_gamma[j] * rsqrtf(c1_var[j] + EPS_);
        const float bias = s1 * c1_b[j] + c1_beta[j] - c1_mean[j] * s1;
        tS[j][tx] = fmaxf(acc[i] + bias, 0.f);
    }
    __syncthreads();
    const int nl = t >> 2, seg = t & 3;
    unsigned short tmp[16];
    #pragma unroll
    for (int j = 0; j < 16; ++j) tmp[j] = f2bf(tS[seg * 16 + j][nl]);
    unsigned short* dst = actT + ((size_t)(b * HW_ + n0 + nl)) * KW2_ + seg * 16;
    *(bf16x8*)(dst)     = *(const bf16x8*)&tmp[0];
    *(bf16x8*)(dst + 8) = *(const bf16x8*)&tmp[8];
}

// ---------------------------------------------------------------------------
// G: conv2 as bf16 MFMA GEMM. out[b,o,n] = relu((s2*W)·act + bias2)
// Block 128x128, 4 waves (2x2), wave tile 64x64 (4x4 of 16x16x32 MFMA).
// grid (32, 4, B), 256 thr.
// ---------------------------------------------------------------------------
__global__ __launch_bounds__(256) void k_conv2_mfma(
        const unsigned short* __restrict__ actT, const float* __restrict__ c2_w,
        const float* __restrict__ c2_b, const float* __restrict__ c2_gamma,
        const float* __restrict__ c2_beta, const float* __restrict__ c2_mean,
        const float* __restrict__ c2_var, float* __restrict__ out) {
    __shared__ __align__(16) unsigned short At[128 * 64];
    __shared__ __align__(16) unsigned short Bt[128 * 64];
    const int t = threadIdx.x;
    const int lane = t & 63, wave = t >> 6;
    const int wr = wave >> 1, wc = wave & 1;
    const int n0 = blockIdx.x * 128, o0 = blockIdx.y * 128, b = blockIdx.z;

    const int srow = t >> 1, shalf = t & 1;
    const int oA = o0 + srow;
    const float s2A = c2_gamma[oA] * rsqrtf(c2_var[oA] + EPS_);

    f32x4 acc[4][4];
    #pragma unroll
    for (int m = 0; m < 4; ++m)
        #pragma unroll
        for (int n = 0; n < 4; ++n) acc[m][n] = (f32x4){0.f, 0.f, 0.f, 0.f};

    for (int ks = 0; ks < 9; ++ks) {
        const int k0 = ks * 64;
        {   // stage A: weights fp32 -> bf16, s2-scaled
            const float4* src = (const float4*)(c2_w + (size_t)oA * KW2_ + k0 + shalf * 32);
            unsigned short tmp[32];
            #pragma unroll
            for (int v = 0; v < 8; ++v) {
                float4 f = src[v];
                tmp[v * 4 + 0] = f2bf(f.x * s2A);
                tmp[v * 4 + 1] = f2bf(f.y * s2A);
                tmp[v * 4 + 2] = f2bf(f.z * s2A);
                tmp[v * 4 + 3] = f2bf(f.w * s2A);
            }
            #pragma unroll
            for (int v = 0; v < 4; ++v) {
                const int kb = shalf * 4 + v;
                *(bf16x8*)&At[srow * 64 + ((kb ^ (srow & 7)) << 3)] =
                    *(const bf16x8*)&tmp[v * 8];
            }
        }
        {   // stage B: actT bf16 direct copy
            const unsigned short* src =
                actT + ((size_t)(b * HW_ + n0 + srow)) * KW2_ + k0 + shalf * 32;
            #pragma unroll
            for (int v = 0; v < 4; ++v) {
                const int kb = shalf * 4 + v;
                *(bf16x8*)&Bt[srow * 64 + ((kb ^ (srow & 7)) << 3)] =
                    *(const bf16x8*)(src + v * 8);
            }
        }
        __syncthreads();
        #pragma unroll
        for (int kk = 0; kk < 2; ++kk) {
            const int g = lane >> 4, a7 = lane & 7, r15 = lane & 15;
            const int kb = kk * 4 + g;
            bf16x8 af[4], bfv[4];
            #pragma unroll
            for (int m = 0; m < 4; ++m) {
                const int row = wr * 64 + m * 16 + r15;
                af[m] = *(const bf16x8*)&At[row * 64 + ((kb ^ a7) << 3)];
            }
            #pragma unroll
            for (int n = 0; n < 4; ++n) {
                const int row = wc * 64 + n * 16 + r15;
                bfv[n] = *(const bf16x8*)&Bt[row * 64 + ((kb ^ a7) << 3)];
            }
            #pragma unroll
            for (int m = 0; m < 4; ++m)
                #pragma unroll
                for (int n = 0; n < 4; ++n)
                    acc[m][n] = __builtin_amdgcn_mfma_f32_16x16x32_bf16(
                        af[m], bfv[n], acc[m][n], 0, 0, 0);
        }
        __syncthreads();
    }
    #pragma unroll
    for (int m = 0; m < 4; ++m) {
        #pragma unroll
        for (int r = 0; r < 4; ++r) {
            const int o = o0 + wr * 64 + m * 16 + (lane >> 4) * 4 + r;
            const float s2 = c2_gamma[o] * rsqrtf(c2_var[o] + EPS_);
            const float bias = s2 * (c2_b[o] - c2_mean[o]) + c2_beta[o];
            float* orow = out + ((size_t)(b * C_ + o)) * HW_ + n0 + wc * 64 + (lane & 15);
            #pragma unroll
            for (int n = 0; n < 4; ++n)
                orow[n * 16] = fmaxf(acc[m][n][r] + bias, 0.f);
        }
    }
}

// ---------------------------------------------------------------------------
// Fallback (fp32 VALU) conv2 path, used only if ws too small for actT.
// ---------------------------------------------------------------------------
__global__ __launch_bounds__(256) void k_fused_out(
        const float* __restrict__ att, const float* __restrict__ Mw,
        const float* __restrict__ c1_b, const float* __restrict__ c1_gamma,
        const float* __restrict__ c1_beta, const float* __restrict__ c1_mean,
        const float* __restrict__ c1_var,
        const float* __restrict__ x, const float* __restrict__ c2_w,
        const float* __restrict__ c2_b, const float* __restrict__ c2_gamma,
        const float* __restrict__ c2_beta, const float* __restrict__ c2_mean,
        const float* __restrict__ c2_var, float* __restrict__ out) {
    __shared__ __align__(16) float sA[64][65];
    __shared__ __align__(16) float sW[64][68];
    __shared__ __align__(16) float tS[64][65];
    const int tx = threadIdx.x, ty = threadIdx.y;
    const int n0 = blockIdx.x * 64, o0 = blockIdx.y * 64, b = blockIdx.z;

    #pragma unroll
    for (int i = 0; i < 16; ++i) {
        const int r = ty * 16 + i;
        sA[r][tx] = att[((size_t)b * C8_ + r) * HW_ + n0 + tx];
        sW[tx][r] = Mw[((size_t)b * 64 + r) * 64 + tx];
    }
    __syncthreads();
    float acc[16];
    #pragma unroll
    for (int i = 0; i < 16; ++i) acc[i] = 0.f;
    #pragma unroll 4
    for (int q = 0; q < 64; ++q)
        FMA16(acc, sA[q][tx], &sW[q][ty * 16]);
    #pragma unroll
    for (int i = 0; i < 16; ++i) {
        const int j = ty * 16 + i;
        const float s1 = c1_gamma[j] * rsqrtf(c1_var[j] + EPS_);
        const float bias = s1 * c1_b[j] + c1_beta[j] - c1_mean[j] * s1;
        tS[j][tx] = fmaxf(acc[i] + bias, 0.f);
    }
    __syncthreads();

    #pragma unroll
    for (int i = 0; i < 16; ++i) acc[i] = 0.f;
    for (int cch = 0; cch < 9; ++cch) {
        #pragma unroll
        for (int i = 0; i < 16; ++i) {
            const int r = ty * 16 + i;
            sW[tx][r] = c2_w[(size_t)(o0 + r) * KW2_ + cch * 64 + tx];
            if (cch > 0)
                sA[r][tx] = x[((size_t)b * C_ + (cch - 1) * 64 + r) * HW_ + n0 + tx];
        }
        __syncthreads();
        const float (*src)[65] = (cch == 0) ? tS : sA;
        #pragma unroll 4
        for (int jj = 0; jj < 64; ++jj)
            FMA16(acc, src[jj][tx], &sW[jj][ty * 16]);
        __syncthreads();
    }
    #pragma unroll
    for (int i = 0; i < 16; ++i) {
        const int o = o0 + ty * 16 + i;
        const float s2 = c2_gamma[o] * rsqrtf(c2_var[o] + EPS_);
        const float v = (acc[i] + c2_b[o]) * s2 + c2_beta[o] - c2_mean[o] * s2;
        out[((size_t)b * C_ + o) * HW_ + n0 + tx] = fmaxf(v, 0.f);
    }
}

extern "C" void kernel_launch(void* const* d_in, const int* in_sizes, int n_in,
                              void* d_out, int out_size, void* d_ws, size_t ws_size,
                              hipStream_t stream) {
    const float* x        = (const float*)d_in[0];
    const float* att      = (const float*)d_in[1];
    const float* key_w    = (const float*)d_in[2];
    const float* key_b    = (const float*)d_in[3];
    const float* c1_w     = (const float*)d_in[4];
    const float* c1_b     = (const float*)d_in[5];
    const float* c1_gamma = (const float*)d_in[6];
    const float* c1_beta  = (const float*)d_in[7];
    const float* c1_mean  = (const float*)d_in[8];
    const float* c1_var   = (const float*)d_in[9];
    const float* c2_w     = (const float*)d_in[10];
    const float* c2_b     = (const float*)d_in[11];
    const float* c2_gamma = (const float*)d_in[12];
    const float* c2_beta  = (const float*)d_in[13];
    const float* c2_mean  = (const float*)d_in[14];
    const float* c2_var   = (const float*)d_in[15];
    float* out = (float*)d_out;

    // ws: M (256 KB) | actT (75.5 MB). epart (16.8 MB) + G (2.1 MB) borrow
    // d_out's head; both fully consumed by k_energy_softmax_M before any
    // kernel writes out (stream-ordered).
    float* M = (float*)d_ws;
    unsigned short* actT = (unsigned short*)((char*)d_ws + 262144);
    const size_t ws_needed = 262144 + (size_t)B_ * HW_ * KW2_ * 2;
    float* epart = out;                      // 16*8*512*64 floats
    float* Gbuf  = out + (size_t)B_ * 8 * 512 * 64;  // 16*512*64 floats

    k_G               <<<dim3(8, 4, B_), 256, 0, stream>>>(x, att, epart);
    k_reduceG         <<<dim3(32, B_),   256, 0, stream>>>(epart, Gbuf);
    k_energy_softmax_M<<<dim3(B_), dim3(64, 4), 0, stream>>>(
        Gbuf, att, key_w, key_b, c1_w, c1_gamma, c1_var, M);

    if (ws_size >= ws_needed) {
        k_xT        <<<dim3(64, 8, B_), 256, 0, stream>>>(x, actT);
        k_t_bf      <<<dim3(64, B_),    256, 0, stream>>>(
            att, M, c1_b, c1_gamma, c1_beta, c1_mean, c1_var, actT);
        k_conv2_mfma<<<dim3(32, 4, B_), 256, 0, stream>>>(
            actT, c2_w, c2_b, c2_gamma, c2_beta, c2_mean, c2_var, out);
    } else {
        k_fused_out<<<dim3(HW_ / 64, C_ / 64, B_), dim3(64, 4), 0, stream>>>(
            att, M, c1_b, c1_gamma, c1_beta, c1_mean, c1_var,
            x, c2_w, c2_b, c2_gamma, c2_beta, c2_mean, c2_var, out);
    }
}

// Round 18
// 241.609 us; speedup vs baseline: 1.3847x; 1.2060x over previous
//
#include <hip/hip_runtime.h>
#include <math.h>

#define B_   16
#define C_   512
#define C8_  64
#define HW_  4096
#define KW2_ 576   // C_ + C8_
#define EPS_ 1e-5f

typedef __attribute__((ext_vector_type(8))) short bf16x8;
typedef __attribute__((ext_vector_type(4))) float f32x4;

__device__ __forceinline__ unsigned short f2bf(float f) {
    union { float f; unsigned u; } v; v.f = f;
    unsigned r = (v.u + 0x7FFFu + ((v.u >> 16) & 1u)) >> 16;  // RNE
    return (unsigned short)r;
}

// 16-output FMA microtile: accv[i] += rowptr[i] * sv (fp32 path)
#define FMA16(accv, sv, rowptr) do {                                            \
    const float4* _w = (const float4*)(rowptr);                                 \
    float4 _w0 = _w[0], _w1 = _w[1], _w2 = _w[2], _w3 = _w[3];                  \
    float _s = (sv);                                                            \
    accv[0]  += _w0.x*_s; accv[1]  += _w0.y*_s; accv[2]  += _w0.z*_s; accv[3]  += _w0.w*_s; \
    accv[4]  += _w1.x*_s; accv[5]  += _w1.y*_s; accv[6]  += _w1.z*_s; accv[7]  += _w1.w*_s; \
    accv[8]  += _w2.x*_s; accv[9]  += _w2.y*_s; accv[10] += _w2.z*_s; accv[11] += _w2.w*_s; \
    accv[12] += _w3.x*_s; accv[13] += _w3.y*_s; accv[14] += _w3.z*_s; accv[15] += _w3.w*_s; \
} while (0)

// ---------------------------------------------------------------------------
// G kernel: epart[b][nc][c][q] = sum_{n in 512-chunk} x[b,c,n]*att[b,q,n]
// bf16 MFMA, both operands n-contiguous in global (transpose-free).
// Block: 128c x 64q, 4 waves (2x2), wave tile 64c x 32q. grid (8, 4, B).
// ---------------------------------------------------------------------------
__global__ __launch_bounds__(256) void k_G(
        const float* __restrict__ x, const float* __restrict__ att,
        float* __restrict__ epart) {
    __shared__ __align__(16) unsigned short Ax[128 * 64]; // x tile [c][n] swz
    __shared__ __align__(16) unsigned short Bq[64 * 64];  // att tile [q][n] swz
    const int t = threadIdx.x;
    const int lane = t & 63, wave = t >> 6;
    const int wr = wave >> 1, wc = wave & 1;
    const int nc = blockIdx.x, c0 = blockIdx.y * 128, b = blockIdx.z;

    f32x4 acc[4][2];
    #pragma unroll
    for (int m = 0; m < 4; ++m)
        #pragma unroll
        for (int n = 0; n < 2; ++n) acc[m][n] = (f32x4){0.f, 0.f, 0.f, 0.f};

    for (int ns = 0; ns < 8; ++ns) {
        const int nb = nc * 512 + ns * 64;
        {   // stage A: x rows (c), 128 rows x 64 n, fp32 -> bf16
            const int row = t >> 1, half = t & 1;
            const float4* src = (const float4*)(x + ((size_t)b * C_ + c0 + row) * HW_ + nb + half * 32);
            unsigned short tmp[32];
            #pragma unroll
            for (int v = 0; v < 8; ++v) {
                float4 f = src[v];
                tmp[v * 4 + 0] = f2bf(f.x); tmp[v * 4 + 1] = f2bf(f.y);
                tmp[v * 4 + 2] = f2bf(f.z); tmp[v * 4 + 3] = f2bf(f.w);
            }
            #pragma unroll
            for (int v = 0; v < 4; ++v) {
                const int kb = half * 4 + v;
                *(bf16x8*)&Ax[row * 64 + ((kb ^ (row & 7)) << 3)] =
                    *(const bf16x8*)&tmp[v * 8];
            }
        }
        {   // stage B: att rows (q), 64 rows x 64 n, fp32 -> bf16
            const int row = t >> 2, qt = t & 3;
            const float4* src = (const float4*)(att + ((size_t)b * C8_ + row) * HW_ + nb + qt * 16);
            unsigned short tmp[16];
            #pragma unroll
            for (int v = 0; v < 4; ++v) {
                float4 f = src[v];
                tmp[v * 4 + 0] = f2bf(f.x); tmp[v * 4 + 1] = f2bf(f.y);
                tmp[v * 4 + 2] = f2bf(f.z); tmp[v * 4 + 3] = f2bf(f.w);
            }
            #pragma unroll
            for (int v = 0; v < 2; ++v) {
                const int kb = qt * 2 + v;
                *(bf16x8*)&Bq[row * 64 + ((kb ^ (row & 7)) << 3)] =
                    *(const bf16x8*)&tmp[v * 8];
            }
        }
        __syncthreads();
        #pragma unroll
        for (int kk = 0; kk < 2; ++kk) {
            const int g = lane >> 4, a7 = lane & 7, r15 = lane & 15;
            const int kb = kk * 4 + g;
            bf16x8 af[4], bfv[2];
            #pragma unroll
            for (int m = 0; m < 4; ++m) {
                const int row = wr * 64 + m * 16 + r15;
                af[m] = *(const bf16x8*)&Ax[row * 64 + ((kb ^ a7) << 3)];
            }
            #pragma unroll
            for (int n = 0; n < 2; ++n) {
                const int row = wc * 32 + n * 16 + r15;
                bfv[n] = *(const bf16x8*)&Bq[row * 64 + ((kb ^ a7) << 3)];
            }
            #pragma unroll
            for (int m = 0; m < 4; ++m)
                #pragma unroll
                for (int n = 0; n < 2; ++n)
                    acc[m][n] = __builtin_amdgcn_mfma_f32_16x16x32_bf16(
                        af[m], bfv[n], acc[m][n], 0, 0, 0);
        }
        __syncthreads();
    }
    // D: row=(lane>>4)*4+i -> c, col=lane&15 -> q
    #pragma unroll
    for (int m = 0; m < 4; ++m) {
        #pragma unroll
        for (int i = 0; i < 4; ++i) {
            const int c = c0 + wr * 64 + m * 16 + (lane >> 4) * 4 + i;
            #pragma unroll
            for (int n = 0; n < 2; ++n) {
                const int q = wc * 32 + n * 16 + (lane & 15);
                epart[((size_t)(b * 8 + nc) * 512 + c) * 64 + q] = acc[m][n][i];
            }
        }
    }
}

// ---------------------------------------------------------------------------
// Reduce 8 n-chunk partials -> G[b][c][q]. grid (32, B), 256 thr.
// ---------------------------------------------------------------------------
__global__ __launch_bounds__(256) void k_reduceG(
        const float* __restrict__ epart, float* __restrict__ G) {
    const int idx4 = blockIdx.x * 256 + threadIdx.x;  // 0..8191 float4s per batch
    const int b = blockIdx.y;
    const float4* e4 = (const float4*)epart;
    float4 s = e4[((size_t)b * 8 + 0) * 8192 + idx4];
    #pragma unroll
    for (int nc = 1; nc < 8; ++nc) {
        float4 v = e4[((size_t)b * 8 + nc) * 8192 + idx4];
        s.x += v.x; s.y += v.y; s.z += v.z; s.w += v.w;
    }
    ((float4*)G)[(size_t)b * 8192 + idx4] = s;
}

// ---------------------------------------------------------------------------
// S kernel: S[b][q] = sum_n att[b,q,n]. grid (C8_, B), 256 thr. Full-chip BW.
// ---------------------------------------------------------------------------
__global__ __launch_bounds__(256) void k_S(
        const float* __restrict__ att, float* __restrict__ S) {
    __shared__ float L[256];
    const int t = threadIdx.x;
    const int q = blockIdx.x, b = blockIdx.y;
    const float4* a4 = (const float4*)(att + ((size_t)b * C8_ + q) * HW_);
    float s = 0.f;
    #pragma unroll
    for (int i = 0; i < 4; ++i) {
        float4 v = a4[t + 256 * i];
        s += v.x + v.y + v.z + v.w;
    }
    L[t] = s;
    __syncthreads();
    if (t < 64) {
        float s4 = L[t] + L[t + 64] + L[t + 128] + L[t + 192];
        #pragma unroll
        for (int off = 32; off > 0; off >>= 1)
            s4 += __shfl_down(s4, off);
        if (t == 0) S[b * C8_ + q] = s4;
    }
}

// ---------------------------------------------------------------------------
// energy = key_w@G + key_b*S; softmax over q; M = s1 (.) (c1_w @ attn).
// grid (B), block (64,4). Sin != nullptr -> read precomputed S.
// ---------------------------------------------------------------------------
__global__ __launch_bounds__(256) void k_energy_softmax_M(
        const float* __restrict__ G, const float* __restrict__ att,
        const float* __restrict__ key_w, const float* __restrict__ key_b,
        const float* __restrict__ c1_w, const float* __restrict__ c1_gamma,
        const float* __restrict__ c1_var, const float* __restrict__ Sin,
        float* __restrict__ M) {
    __shared__ __align__(16) float bufA[64][65];  // kwS[k][c] -> attnS[k][q]
    __shared__ __align__(16) float bufB[64][68];  // GT[c][q]  -> c1T[k][o]
    __shared__ __align__(16) float eT[64][65];    // S-scratch -> energy [q][k]
    __shared__ float Ssh[64];
    const int tx = threadIdx.x, ty = threadIdx.y;
    const int t = ty * 64 + tx;
    const int b = blockIdx.x;

    if (Sin) {
        if (t < 64) Ssh[t] = Sin[b * C8_ + t];
    } else {
        {   // S[q] = sum_n att[b,q,n], 4 partials per q
            const int q = t & 63, part = t >> 6;
            const float4* a4 = (const float4*)(att + ((size_t)b * C8_ + q) * HW_) + part * 256;
            float s = 0.f;
            for (int i = 0; i < 256; ++i) { float4 v = a4[i]; s += v.x + v.y + v.z + v.w; }
            eT[part][q] = s;
        }
        __syncthreads();
        if (t < 64) Ssh[t] = eT[0][t] + eT[1][t] + eT[2][t] + eT[3][t];
    }

    // energy accumulation: eacc[j]: k=tx, q=ty*16+j
    float eacc[16];
    #pragma unroll
    for (int i = 0; i < 16; ++i) eacc[i] = 0.f;
    for (int cc8 = 0; cc8 < 8; ++cc8) {
        const int c0 = cc8 * 64;
        #pragma unroll
        for (int i = 0; i < 16; ++i) {
            const int r = ty * 16 + i;
            bufA[r][tx] = key_w[(size_t)r * C_ + c0 + tx];          // kwS[k][c]
            bufB[r][tx] = G[((size_t)b * C_ + c0 + r) * 64 + tx];   // GT[c][q]
        }
        __syncthreads();
        #pragma unroll 4
        for (int cl = 0; cl < 64; ++cl)
            FMA16(eacc, bufA[tx][cl], &bufB[cl][ty * 16]);
        __syncthreads();
    }
    // store energy as eT[q][k]; load c1T into bufB
    #pragma unroll
    for (int j = 0; j < 16; ++j) {
        const int q = ty * 16 + j;
        eT[q][tx] = eacc[j] + key_b[tx] * Ssh[q];
    }
    #pragma unroll
    for (int i = 0; i < 16; ++i) {
        const int oo = ty * 16 + i;
        bufB[tx][oo] = c1_w[oo * 64 + tx];   // c1T[k][o]
    }
    __syncthreads();

    if (t < 64) {    // softmax over q per k-row -> attnS in bufA[k][q]
        const int k = t;
        float m = -1e30f;
        for (int q = 0; q < 64; ++q) m = fmaxf(m, eT[q][k]);
        float s = 0.f;
        for (int q = 0; q < 64; ++q) {
            const float p = __expf(eT[q][k] - m);
            bufA[k][q] = p;
            s += p;
        }
        const float inv = 1.f / s;
        for (int q = 0; q < 64; ++q) bufA[k][q] *= inv;
    }
    __syncthreads();

    float acc[16];
    #pragma unroll
    for (int i = 0; i < 16; ++i) acc[i] = 0.f;
    #pragma unroll 4
    for (int k = 0; k < 64; ++k)
        FMA16(acc, bufA[k][tx], &bufB[k][ty * 16]);   // acc[i]: o=ty*16+i, q=tx
    #pragma unroll
    for (int i = 0; i < 16; ++i) {
        const int o = ty * 16 + i;
        const float s1 = c1_gamma[o] * rsqrtf(c1_var[o] + EPS_);
        M[((size_t)b * 64 + o) * 64 + tx] = s1 * acc[i];
    }
}

// ---------------------------------------------------------------------------
// T1: transpose-convert x -> actT[b][n][C8_+c] bf16. grid (64, 8, B), 256 thr.
// ---------------------------------------------------------------------------
__global__ __launch_bounds__(256) void k_xT(
        const float* __restrict__ x, unsigned short* __restrict__ actT) {
    __shared__ float S[64][65];
    const int t = threadIdx.x;
    const int tx = t & 63, ty = t >> 6;
    const int n0 = blockIdx.x * 64, c0 = blockIdx.y * 64, b = blockIdx.z;
    #pragma unroll
    for (int i = 0; i < 16; ++i) {
        const int r = ty * 16 + i;
        S[r][tx] = x[((size_t)(b * C_ + c0 + r)) * HW_ + n0 + tx];
    }
    __syncthreads();
    const int nl = t >> 2, seg = t & 3;
    unsigned short tmp[16];
    #pragma unroll
    for (int j = 0; j < 16; ++j) tmp[j] = f2bf(S[seg * 16 + j][nl]);
    unsigned short* dst = actT + ((size_t)(b * HW_ + n0 + nl)) * KW2_ + C8_ + c0 + seg * 16;
    *(bf16x8*)(dst)     = *(const bf16x8*)&tmp[0];
    *(bf16x8*)(dst + 8) = *(const bf16x8*)&tmp[8];
}

// ---------------------------------------------------------------------------
// T2: t[j,n] = relu(sum_q M[b,j,q]*att[b,q,n] + bias1[j]) -> actT[b][n][j] bf16
// grid (64, B), 256 thr.
// ---------------------------------------------------------------------------
__global__ __launch_bounds__(256) void k_t_bf(
        const float* __restrict__ att, const float* __restrict__ Mw,
        const float* __restrict__ c1_b, const float* __restrict__ c1_gamma,
        const float* __restrict__ c1_beta, const float* __restrict__ c1_mean,
        const float* __restrict__ c1_var, unsigned short* __restrict__ actT) {
    __shared__ __align__(16) float attS[64][65];
    __shared__ __align__(16) float MT[64][68];
    __shared__ float tS[64][65];
    const int t = threadIdx.x;
    const int tx = t & 63, ty = t >> 6;
    const int n0 = blockIdx.x * 64, b = blockIdx.y;

    #pragma unroll
    for (int i = 0; i < 16; ++i) {
        const int r = ty * 16 + i;
        attS[r][tx] = att[((size_t)b * C8_ + r) * HW_ + n0 + tx];
        MT[tx][r]   = Mw[((size_t)b * 64 + r) * 64 + tx];
    }
    __syncthreads();
    float acc[16];
    #pragma unroll
    for (int i = 0; i < 16; ++i) acc[i] = 0.f;
    #pragma unroll 4
    for (int q = 0; q < 64; ++q)
        FMA16(acc, attS[q][tx], &MT[q][ty * 16]);
    #pragma unroll
    for (int i = 0; i < 16; ++i) {
        const int j = ty * 16 + i;
        const float s1 = c1_gamma[j] * rsqrtf(c1_var[j] + EPS_);
        const float bias = s1 * c1_b[j] + c1_beta[j] - c1_mean[j] * s1;
        tS[j][tx] = fmaxf(acc[i] + bias, 0.f);
    }
    __syncthreads();
    const int nl = t >> 2, seg = t & 3;
    unsigned short tmp[16];
    #pragma unroll
    for (int j = 0; j < 16; ++j) tmp[j] = f2bf(tS[seg * 16 + j][nl]);
    unsigned short* dst = actT + ((size_t)(b * HW_ + n0 + nl)) * KW2_ + seg * 16;
    *(bf16x8*)(dst)     = *(const bf16x8*)&tmp[0];
    *(bf16x8*)(dst + 8) = *(const bf16x8*)&tmp[8];
}

// ---------------------------------------------------------------------------
// W: pre-convert weights: wbf[o][k] = bf16(c2_w[o][k] * s2[o]).
// grid (144), 256 thr; each thread one 8-elem segment (512*72 = 36864 segs).
// ---------------------------------------------------------------------------
__global__ __launch_bounds__(256) void k_wbf(
        const float* __restrict__ c2_w, const float* __restrict__ c2_gamma,
        const float* __restrict__ c2_var, unsigned short* __restrict__ wbf) {
    const int seg = blockIdx.x * 256 + threadIdx.x;   // < 36864
    const int o = seg / 72, ks = (seg % 72) * 8;
    const float s2 = c2_gamma[o] * rsqrtf(c2_var[o] + EPS_);
    const float4* src = (const float4*)(c2_w + (size_t)o * KW2_ + ks);
    float4 f0 = src[0], f1 = src[1];
    unsigned short tmp[8];
    tmp[0] = f2bf(f0.x * s2); tmp[1] = f2bf(f0.y * s2);
    tmp[2] = f2bf(f0.z * s2); tmp[3] = f2bf(f0.w * s2);
    tmp[4] = f2bf(f1.x * s2); tmp[5] = f2bf(f1.y * s2);
    tmp[6] = f2bf(f1.z * s2); tmp[7] = f2bf(f1.w * s2);
    *(bf16x8*)(wbf + (size_t)o * KW2_ + ks) = *(const bf16x8*)tmp;
}

// ---------------------------------------------------------------------------
// conv2 (wbf variant): both A and B staged as pure bf16 16B copies.
// Block 128x128, 4 waves (2x2), wave tile 64x64. grid (32, 4, B), 256 thr.
// ---------------------------------------------------------------------------
__global__ __launch_bounds__(256) void k_conv2_wbf(
        const unsigned short* __restrict__ actT, const unsigned short* __restrict__ wbf,
        const float* __restrict__ c2_b, const float* __restrict__ c2_gamma,
        const float* __restrict__ c2_beta, const float* __restrict__ c2_mean,
        const float* __restrict__ c2_var, float* __restrict__ out) {
    __shared__ __align__(16) unsigned short At[128 * 64];
    __shared__ __align__(16) unsigned short Bt[128 * 64];
    const int t = threadIdx.x;
    const int lane = t & 63, wave = t >> 6;
    const int wr = wave >> 1, wc = wave & 1;
    const int n0 = blockIdx.x * 128, o0 = blockIdx.y * 128, b = blockIdx.z;
    const int srow = t >> 1, shalf = t & 1;

    f32x4 acc[4][4];
    #pragma unroll
    for (int m = 0; m < 4; ++m)
        #pragma unroll
        for (int n = 0; n < 4; ++n) acc[m][n] = (f32x4){0.f, 0.f, 0.f, 0.f};

    for (int ks = 0; ks < 9; ++ks) {
        const int k0 = ks * 64;
        {   // stage A: weights bf16 direct copy
            const unsigned short* src =
                wbf + (size_t)(o0 + srow) * KW2_ + k0 + shalf * 32;
            #pragma unroll
            for (int v = 0; v < 4; ++v) {
                const int kb = shalf * 4 + v;
                *(bf16x8*)&At[srow * 64 + ((kb ^ (srow & 7)) << 3)] =
                    *(const bf16x8*)(src + v * 8);
            }
        }
        {   // stage B: actT bf16 direct copy
            const unsigned short* src =
                actT + ((size_t)(b * HW_ + n0 + srow)) * KW2_ + k0 + shalf * 32;
            #pragma unroll
            for (int v = 0; v < 4; ++v) {
                const int kb = shalf * 4 + v;
                *(bf16x8*)&Bt[srow * 64 + ((kb ^ (srow & 7)) << 3)] =
                    *(const bf16x8*)(src + v * 8);
            }
        }
        __syncthreads();
        #pragma unroll
        for (int kk = 0; kk < 2; ++kk) {
            const int g = lane >> 4, a7 = lane & 7, r15 = lane & 15;
            const int kb = kk * 4 + g;
            bf16x8 af[4], bfv[4];
            #pragma unroll
            for (int m = 0; m < 4; ++m) {
                const int row = wr * 64 + m * 16 + r15;
                af[m] = *(const bf16x8*)&At[row * 64 + ((kb ^ a7) << 3)];
            }
            #pragma unroll
            for (int n = 0; n < 4; ++n) {
                const int row = wc * 64 + n * 16 + r15;
                bfv[n] = *(const bf16x8*)&Bt[row * 64 + ((kb ^ a7) << 3)];
            }
            #pragma unroll
            for (int m = 0; m < 4; ++m)
                #pragma unroll
                for (int n = 0; n < 4; ++n)
                    acc[m][n] = __builtin_amdgcn_mfma_f32_16x16x32_bf16(
                        af[m], bfv[n], acc[m][n], 0, 0, 0);
        }
        __syncthreads();
    }
    #pragma unroll
    for (int m = 0; m < 4; ++m) {
        #pragma unroll
        for (int r = 0; r < 4; ++r) {
            const int o = o0 + wr * 64 + m * 16 + (lane >> 4) * 4 + r;
            const float s2 = c2_gamma[o] * rsqrtf(c2_var[o] + EPS_);
            const float bias = s2 * (c2_b[o] - c2_mean[o]) + c2_beta[o];
            float* orow = out + ((size_t)(b * C_ + o)) * HW_ + n0 + wc * 64 + (lane & 15);
            #pragma unroll
            for (int n = 0; n < 4; ++n)
                orow[n * 16] = fmaxf(acc[m][n][r] + bias, 0.f);
        }
    }
}

// ---------------------------------------------------------------------------
// conv2 (legacy, fp32 weights staged in-kernel) — mid ws path.
// ---------------------------------------------------------------------------
__global__ __launch_bounds__(256) void k_conv2_mfma(
        const unsigned short* __restrict__ actT, const float* __restrict__ c2_w,
        const float* __restrict__ c2_b, const float* __restrict__ c2_gamma,
        const float* __restrict__ c2_beta, const float* __restrict__ c2_mean,
        const float* __restrict__ c2_var, float* __restrict__ out) {
    __shared__ __align__(16) unsigned short At[128 * 64];
    __shared__ __align__(16) unsigned short Bt[128 * 64];
    const int t = threadIdx.x;
    const int lane = t & 63, wave = t >> 6;
    const int wr = wave >> 1, wc = wave & 1;
    const int n0 = blockIdx.x * 128, o0 = blockIdx.y * 128, b = blockIdx.z;
    const int srow = t >> 1, shalf = t & 1;
    const int oA = o0 + srow;
    const float s2A = c2_gamma[oA] * rsqrtf(c2_var[oA] + EPS_);

    f32x4 acc[4][4];
    #pragma unroll
    for (int m = 0; m < 4; ++m)
        #pragma unroll
        for (int n = 0; n < 4; ++n) acc[m][n] = (f32x4){0.f, 0.f, 0.f, 0.f};

    for (int ks = 0; ks < 9; ++ks) {
        const int k0 = ks * 64;
        {
            const float4* src = (const float4*)(c2_w + (size_t)oA * KW2_ + k0 + shalf * 32);
            unsigned short tmp[32];
            #pragma unroll
            for (int v = 0; v < 8; ++v) {
                float4 f = src[v];
                tmp[v * 4 + 0] = f2bf(f.x * s2A);
                tmp[v * 4 + 1] = f2bf(f.y * s2A);
                tmp[v * 4 + 2] = f2bf(f.z * s2A);
                tmp[v * 4 + 3] = f2bf(f.w * s2A);
            }
            #pragma unroll
            for (int v = 0; v < 4; ++v) {
                const int kb = shalf * 4 + v;
                *(bf16x8*)&At[srow * 64 + ((kb ^ (srow & 7)) << 3)] =
                    *(const bf16x8*)&tmp[v * 8];
            }
        }
        {
            const unsigned short* src =
                actT + ((size_t)(b * HW_ + n0 + srow)) * KW2_ + k0 + shalf * 32;
            #pragma unroll
            for (int v = 0; v < 4; ++v) {
                const int kb = shalf * 4 + v;
                *(bf16x8*)&Bt[srow * 64 + ((kb ^ (srow & 7)) << 3)] =
                    *(const bf16x8*)(src + v * 8);
            }
        }
        __syncthreads();
        #pragma unroll
        for (int kk = 0; kk < 2; ++kk) {
            const int g = lane >> 4, a7 = lane & 7, r15 = lane & 15;
            const int kb = kk * 4 + g;
            bf16x8 af[4], bfv[4];
            #pragma unroll
            for (int m = 0; m < 4; ++m) {
                const int row = wr * 64 + m * 16 + r15;
                af[m] = *(const bf16x8*)&At[row * 64 + ((kb ^ a7) << 3)];
            }
            #pragma unroll
            for (int n = 0; n < 4; ++n) {
                const int row = wc * 64 + n * 16 + r15;
                bfv[n] = *(const bf16x8*)&Bt[row * 64 + ((kb ^ a7) << 3)];
            }
            #pragma unroll
            for (int m = 0; m < 4; ++m)
                #pragma unroll
                for (int n = 0; n < 4; ++n)
                    acc[m][n] = __builtin_amdgcn_mfma_f32_16x16x32_bf16(
                        af[m], bfv[n], acc[m][n], 0, 0, 0);
        }
        __syncthreads();
    }
    #pragma unroll
    for (int m = 0; m < 4; ++m) {
        #pragma unroll
        for (int r = 0; r < 4; ++r) {
            const int o = o0 + wr * 64 + m * 16 + (lane >> 4) * 4 + r;
            const float s2 = c2_gamma[o] * rsqrtf(c2_var[o] + EPS_);
            const float bias = s2 * (c2_b[o] - c2_mean[o]) + c2_beta[o];
            float* orow = out + ((size_t)(b * C_ + o)) * HW_ + n0 + wc * 64 + (lane & 15);
            #pragma unroll
            for (int n = 0; n < 4; ++n)
                orow[n * 16] = fmaxf(acc[m][n][r] + bias, 0.f);
        }
    }
}

// ---------------------------------------------------------------------------
// Fallback (fp32 VALU) conv2 path, used only if ws too small for actT.
// ---------------------------------------------------------------------------
__global__ __launch_bounds__(256) void k_fused_out(
        const float* __restrict__ att, const float* __restrict__ Mw,
        const float* __restrict__ c1_b, const float* __restrict__ c1_gamma,
        const float* __restrict__ c1_beta, const float* __restrict__ c1_mean,
        const float* __restrict__ c1_var,
        const float* __restrict__ x, const float* __restrict__ c2_w,
        const float* __restrict__ c2_b, const float* __restrict__ c2_gamma,
        const float* __restrict__ c2_beta, const float* __restrict__ c2_mean,
        const float* __restrict__ c2_var, float* __restrict__ out) {
    __shared__ __align__(16) float sA[64][65];
    __shared__ __align__(16) float sW[64][68];
    __shared__ __align__(16) float tS[64][65];
    const int tx = threadIdx.x, ty = threadIdx.y;
    const int n0 = blockIdx.x * 64, o0 = blockIdx.y * 64, b = blockIdx.z;

    #pragma unroll
    for (int i = 0; i < 16; ++i) {
        const int r = ty * 16 + i;
        sA[r][tx] = att[((size_t)b * C8_ + r) * HW_ + n0 + tx];
        sW[tx][r] = Mw[((size_t)b * 64 + r) * 64 + tx];
    }
    __syncthreads();
    float acc[16];
    #pragma unroll
    for (int i = 0; i < 16; ++i) acc[i] = 0.f;
    #pragma unroll 4
    for (int q = 0; q < 64; ++q)
        FMA16(acc, sA[q][tx], &sW[q][ty * 16]);
    #pragma unroll
    for (int i = 0; i < 16; ++i) {
        const int j = ty * 16 + i;
        const float s1 = c1_gamma[j] * rsqrtf(c1_var[j] + EPS_);
        const float bias = s1 * c1_b[j] + c1_beta[j] - c1_mean[j] * s1;
        tS[j][tx] = fmaxf(acc[i] + bias, 0.f);
    }
    __syncthreads();

    #pragma unroll
    for (int i = 0; i < 16; ++i) acc[i] = 0.f;
    for (int cch = 0; cch < 9; ++cch) {
        #pragma unroll
        for (int i = 0; i < 16; ++i) {
            const int r = ty * 16 + i;
            sW[tx][r] = c2_w[(size_t)(o0 + r) * KW2_ + cch * 64 + tx];
            if (cch > 0)
                sA[r][tx] = x[((size_t)b * C_ + (cch - 1) * 64 + r) * HW_ + n0 + tx];
        }
        __syncthreads();
        const float (*src)[65] = (cch == 0) ? tS : sA;
        #pragma unroll 4
        for (int jj = 0; jj < 64; ++jj)
            FMA16(acc, src[jj][tx], &sW[jj][ty * 16]);
        __syncthreads();
    }
    #pragma unroll
    for (int i = 0; i < 16; ++i) {
        const int o = o0 + ty * 16 + i;
        const float s2 = c2_gamma[o] * rsqrtf(c2_var[o] + EPS_);
        const float v = (acc[i] + c2_b[o]) * s2 + c2_beta[o] - c2_mean[o] * s2;
        out[((size_t)b * C_ + o) * HW_ + n0 + tx] = fmaxf(v, 0.f);
    }
}

extern "C" void kernel_launch(void* const* d_in, const int* in_sizes, int n_in,
                              void* d_out, int out_size, void* d_ws, size_t ws_size,
                              hipStream_t stream) {
    const float* x        = (const float*)d_in[0];
    const float* att      = (const float*)d_in[1];
    const float* key_w    = (const float*)d_in[2];
    const float* key_b    = (const float*)d_in[3];
    const float* c1_w     = (const float*)d_in[4];
    const float* c1_b     = (const float*)d_in[5];
    const float* c1_gamma = (const float*)d_in[6];
    const float* c1_beta  = (const float*)d_in[7];
    const float* c1_mean  = (const float*)d_in[8];
    const float* c1_var   = (const float*)d_in[9];
    const float* c2_w     = (const float*)d_in[10];
    const float* c2_b     = (const float*)d_in[11];
    const float* c2_gamma = (const float*)d_in[12];
    const float* c2_beta  = (const float*)d_in[13];
    const float* c2_mean  = (const float*)d_in[14];
    const float* c2_var   = (const float*)d_in[15];
    float* out = (float*)d_out;

    // ws: M (256KB) | actT (75.5MB) | wbf (590KB) | S (4KB)
    const size_t off_actT = 262144;
    const size_t off_wbf  = off_actT + (size_t)B_ * HW_ * KW2_ * 2;
    const size_t off_S    = off_wbf + (size_t)C_ * KW2_ * 2;
    const size_t ws_full  = off_S + (size_t)B_ * C8_ * 4;
    const size_t ws_mid   = off_wbf;

    float* M = (float*)d_ws;
    unsigned short* actT = (unsigned short*)((char*)d_ws + off_actT);
    unsigned short* wbf  = (unsigned short*)((char*)d_ws + off_wbf);
    float* Sbuf          = (float*)((char*)d_ws + off_S);

    // epart (16.8MB) + G (2.1MB) borrow d_out's head; both fully consumed by
    // k_energy_softmax_M before any kernel writes out (stream-ordered).
    float* epart = out;
    float* Gbuf  = out + (size_t)B_ * 8 * 512 * 64;

    k_G      <<<dim3(8, 4, B_), 256, 0, stream>>>(x, att, epart);
    k_reduceG<<<dim3(32, B_),   256, 0, stream>>>(epart, Gbuf);

    if (ws_size >= ws_full) {
        k_S<<<dim3(C8_, B_), 256, 0, stream>>>(att, Sbuf);
        k_energy_softmax_M<<<dim3(B_), dim3(64, 4), 0, stream>>>(
            Gbuf, att, key_w, key_b, c1_w, c1_gamma, c1_var, Sbuf, M);
        k_xT  <<<dim3(64, 8, B_), 256, 0, stream>>>(x, actT);
        k_t_bf<<<dim3(64, B_),    256, 0, stream>>>(
            att, M, c1_b, c1_gamma, c1_beta, c1_mean, c1_var, actT);
        k_wbf <<<dim3(144),       256, 0, stream>>>(c2_w, c2_gamma, c2_var, wbf);
        k_conv2_wbf<<<dim3(32, 4, B_), 256, 0, stream>>>(
            actT, wbf, c2_b, c2_gamma, c2_beta, c2_mean, c2_var, out);
    } else if (ws_size >= ws_mid) {
        k_energy_softmax_M<<<dim3(B_), dim3(64, 4), 0, stream>>>(
            Gbuf, att, key_w, key_b, c1_w, c1_gamma, c1_var, nullptr, M);
        k_xT  <<<dim3(64, 8, B_), 256, 0, stream>>>(x, actT);
        k_t_bf<<<dim3(64, B_),    256, 0, stream>>>(
            att, M, c1_b, c1_gamma, c1_beta, c1_mean, c1_var, actT);
        k_conv2_mfma<<<dim3(32, 4, B_), 256, 0, stream>>>(
            actT, c2_w, c2_b, c2_gamma, c2_beta, c2_mean, c2_var, out);
    } else {
        k_energy_softmax_M<<<dim3(B_), dim3(64, 4), 0, stream>>>(
            Gbuf, att, key_w, key_b, c1_w, c1_gamma, c1_var, nullptr, M);
        k_fused_out<<<dim3(HW_ / 64, C_ / 64, B_), dim3(64, 4), 0, stream>>>(
            att, M, c1_b, c1_gamma, c1_beta, c1_mean, c1_var,
            x, c2_w, c2_b, c2_gamma, c2_beta, c2_mean, c2_var, out);
    }
}

// Round 19
// 232.980 us; speedup vs baseline: 1.4360x; 1.0370x over previous
//
#include <hip/hip_runtime.h>
#include <math.h>

#define B_   16
#define C_   512
#define C8_  64
#define HW_  4096
#define KW2_ 576   // C_ + C8_
#define EPS_ 1e-5f

typedef __attribute__((ext_vector_type(8))) short bf16x8;
typedef __attribute__((ext_vector_type(4))) float f32x4;

__device__ __forceinline__ unsigned short f2bf(float f) {
    union { float f; unsigned u; } v; v.f = f;
    unsigned r = (v.u + 0x7FFFu + ((v.u >> 16) & 1u)) >> 16;  // RNE
    return (unsigned short)r;
}

// 16-output FMA microtile: accv[i] += rowptr[i] * sv (fp32 path)
#define FMA16(accv, sv, rowptr) do {                                            \
    const float4* _w = (const float4*)(rowptr);                                 \
    float4 _w0 = _w[0], _w1 = _w[1], _w2 = _w[2], _w3 = _w[3];                  \
    float _s = (sv);                                                            \
    accv[0]  += _w0.x*_s; accv[1]  += _w0.y*_s; accv[2]  += _w0.z*_s; accv[3]  += _w0.w*_s; \
    accv[4]  += _w1.x*_s; accv[5]  += _w1.y*_s; accv[6]  += _w1.z*_s; accv[7]  += _w1.w*_s; \
    accv[8]  += _w2.x*_s; accv[9]  += _w2.y*_s; accv[10] += _w2.z*_s; accv[11] += _w2.w*_s; \
    accv[12] += _w3.x*_s; accv[13] += _w3.y*_s; accv[14] += _w3.z*_s; accv[15] += _w3.w*_s; \
} while (0)

// ---------------------------------------------------------------------------
// G kernel: epart[b][nc][c][q] = sum_{n in 512-chunk} x[b,c,n]*att[b,q,n]
// bf16 MFMA, both operands n-contiguous in global (transpose-free).
// Block: 128c x 64q, 4 waves (2x2), wave tile 64c x 32q. grid (8, 4, B).
// ---------------------------------------------------------------------------
__global__ __launch_bounds__(256) void k_G(
        const float* __restrict__ x, const float* __restrict__ att,
        float* __restrict__ epart) {
    __shared__ __align__(16) unsigned short Ax[128 * 64]; // x tile [c][n] swz
    __shared__ __align__(16) unsigned short Bq[64 * 64];  // att tile [q][n] swz
    const int t = threadIdx.x;
    const int lane = t & 63, wave = t >> 6;
    const int wr = wave >> 1, wc = wave & 1;
    const int nc = blockIdx.x, c0 = blockIdx.y * 128, b = blockIdx.z;

    f32x4 acc[4][2];
    #pragma unroll
    for (int m = 0; m < 4; ++m)
        #pragma unroll
        for (int n = 0; n < 2; ++n) acc[m][n] = (f32x4){0.f, 0.f, 0.f, 0.f};

    for (int ns = 0; ns < 8; ++ns) {
        const int nb = nc * 512 + ns * 64;
        {   // stage A: x rows (c), 128 rows x 64 n, fp32 -> bf16
            const int row = t >> 1, half = t & 1;
            const float4* src = (const float4*)(x + ((size_t)b * C_ + c0 + row) * HW_ + nb + half * 32);
            unsigned short tmp[32];
            #pragma unroll
            for (int v = 0; v < 8; ++v) {
                float4 f = src[v];
                tmp[v * 4 + 0] = f2bf(f.x); tmp[v * 4 + 1] = f2bf(f.y);
                tmp[v * 4 + 2] = f2bf(f.z); tmp[v * 4 + 3] = f2bf(f.w);
            }
            #pragma unroll
            for (int v = 0; v < 4; ++v) {
                const int kb = half * 4 + v;
                *(bf16x8*)&Ax[row * 64 + ((kb ^ (row & 7)) << 3)] =
                    *(const bf16x8*)&tmp[v * 8];
            }
        }
        {   // stage B: att rows (q), 64 rows x 64 n, fp32 -> bf16
            const int row = t >> 2, qt = t & 3;
            const float4* src = (const float4*)(att + ((size_t)b * C8_ + row) * HW_ + nb + qt * 16);
            unsigned short tmp[16];
            #pragma unroll
            for (int v = 0; v < 4; ++v) {
                float4 f = src[v];
                tmp[v * 4 + 0] = f2bf(f.x); tmp[v * 4 + 1] = f2bf(f.y);
                tmp[v * 4 + 2] = f2bf(f.z); tmp[v * 4 + 3] = f2bf(f.w);
            }
            #pragma unroll
            for (int v = 0; v < 2; ++v) {
                const int kb = qt * 2 + v;
                *(bf16x8*)&Bq[row * 64 + ((kb ^ (row & 7)) << 3)] =
                    *(const bf16x8*)&tmp[v * 8];
            }
        }
        __syncthreads();
        #pragma unroll
        for (int kk = 0; kk < 2; ++kk) {
            const int g = lane >> 4, a7 = lane & 7, r15 = lane & 15;
            const int kb = kk * 4 + g;
            bf16x8 af[4], bfv[2];
            #pragma unroll
            for (int m = 0; m < 4; ++m) {
                const int row = wr * 64 + m * 16 + r15;
                af[m] = *(const bf16x8*)&Ax[row * 64 + ((kb ^ a7) << 3)];
            }
            #pragma unroll
            for (int n = 0; n < 2; ++n) {
                const int row = wc * 32 + n * 16 + r15;
                bfv[n] = *(const bf16x8*)&Bq[row * 64 + ((kb ^ a7) << 3)];
            }
            #pragma unroll
            for (int m = 0; m < 4; ++m)
                #pragma unroll
                for (int n = 0; n < 2; ++n)
                    acc[m][n] = __builtin_amdgcn_mfma_f32_16x16x32_bf16(
                        af[m], bfv[n], acc[m][n], 0, 0, 0);
        }
        __syncthreads();
    }
    // D: row=(lane>>4)*4+i -> c, col=lane&15 -> q
    #pragma unroll
    for (int m = 0; m < 4; ++m) {
        #pragma unroll
        for (int i = 0; i < 4; ++i) {
            const int c = c0 + wr * 64 + m * 16 + (lane >> 4) * 4 + i;
            #pragma unroll
            for (int n = 0; n < 2; ++n) {
                const int q = wc * 32 + n * 16 + (lane & 15);
                epart[((size_t)(b * 8 + nc) * 512 + c) * 64 + q] = acc[m][n][i];
            }
        }
    }
}

// ---------------------------------------------------------------------------
// Reduce 8 n-chunk partials -> G[b][c][q]. grid (32, B), 256 thr.
// ---------------------------------------------------------------------------
__global__ __launch_bounds__(256) void k_reduceG(
        const float* __restrict__ epart, float* __restrict__ G) {
    const int idx4 = blockIdx.x * 256 + threadIdx.x;  // 0..8191 float4s per batch
    const int b = blockIdx.y;
    const float4* e4 = (const float4*)epart;
    float4 s = e4[((size_t)b * 8 + 0) * 8192 + idx4];
    #pragma unroll
    for (int nc = 1; nc < 8; ++nc) {
        float4 v = e4[((size_t)b * 8 + nc) * 8192 + idx4];
        s.x += v.x; s.y += v.y; s.z += v.z; s.w += v.w;
    }
    ((float4*)G)[(size_t)b * 8192 + idx4] = s;
}

// ---------------------------------------------------------------------------
// S kernel: S[b][q] = sum_n att[b,q,n]. grid (C8_, B), 256 thr. Full-chip BW.
// ---------------------------------------------------------------------------
__global__ __launch_bounds__(256) void k_S(
        const float* __restrict__ att, float* __restrict__ S) {
    __shared__ float L[256];
    const int t = threadIdx.x;
    const int q = blockIdx.x, b = blockIdx.y;
    const float4* a4 = (const float4*)(att + ((size_t)b * C8_ + q) * HW_);
    float s = 0.f;
    #pragma unroll
    for (int i = 0; i < 4; ++i) {
        float4 v = a4[t + 256 * i];
        s += v.x + v.y + v.z + v.w;
    }
    L[t] = s;
    __syncthreads();
    if (t < 64) {
        float s4 = L[t] + L[t + 64] + L[t + 128] + L[t + 192];
        #pragma unroll
        for (int off = 32; off > 0; off >>= 1)
            s4 += __shfl_down(s4, off);
        if (t == 0) S[b * C8_ + q] = s4;
    }
}

// ---------------------------------------------------------------------------
// energy = key_w@G + key_b*S; softmax over q; M = s1 (.) (c1_w @ attn).
// grid (B), block (64,4). Sin != nullptr -> read precomputed S.
// ---------------------------------------------------------------------------
__global__ __launch_bounds__(256) void k_energy_softmax_M(
        const float* __restrict__ G, const float* __restrict__ att,
        const float* __restrict__ key_w, const float* __restrict__ key_b,
        const float* __restrict__ c1_w, const float* __restrict__ c1_gamma,
        const float* __restrict__ c1_var, const float* __restrict__ Sin,
        float* __restrict__ M) {
    __shared__ __align__(16) float bufA[64][65];  // kwS[k][c] -> attnS[k][q]
    __shared__ __align__(16) float bufB[64][68];  // GT[c][q]  -> c1T[k][o]
    __shared__ __align__(16) float eT[64][65];    // S-scratch -> energy [q][k]
    __shared__ float Ssh[64];
    const int tx = threadIdx.x, ty = threadIdx.y;
    const int t = ty * 64 + tx;
    const int b = blockIdx.x;

    if (Sin) {
        if (t < 64) Ssh[t] = Sin[b * C8_ + t];
    } else {
        {   // S[q] = sum_n att[b,q,n], 4 partials per q
            const int q = t & 63, part = t >> 6;
            const float4* a4 = (const float4*)(att + ((size_t)b * C8_ + q) * HW_) + part * 256;
            float s = 0.f;
            for (int i = 0; i < 256; ++i) { float4 v = a4[i]; s += v.x + v.y + v.z + v.w; }
            eT[part][q] = s;
        }
        __syncthreads();
        if (t < 64) Ssh[t] = eT[0][t] + eT[1][t] + eT[2][t] + eT[3][t];
    }

    // energy accumulation: eacc[j]: k=tx, q=ty*16+j
    float eacc[16];
    #pragma unroll
    for (int i = 0; i < 16; ++i) eacc[i] = 0.f;
    for (int cc8 = 0; cc8 < 8; ++cc8) {
        const int c0 = cc8 * 64;
        #pragma unroll
        for (int i = 0; i < 16; ++i) {
            const int r = ty * 16 + i;
            bufA[r][tx] = key_w[(size_t)r * C_ + c0 + tx];          // kwS[k][c]
            bufB[r][tx] = G[((size_t)b * C_ + c0 + r) * 64 + tx];   // GT[c][q]
        }
        __syncthreads();
        #pragma unroll 4
        for (int cl = 0; cl < 64; ++cl)
            FMA16(eacc, bufA[tx][cl], &bufB[cl][ty * 16]);
        __syncthreads();
    }
    // store energy as eT[q][k]; load c1T into bufB
    #pragma unroll
    for (int j = 0; j < 16; ++j) {
        const int q = ty * 16 + j;
        eT[q][tx] = eacc[j] + key_b[tx] * Ssh[q];
    }
    #pragma unroll
    for (int i = 0; i < 16; ++i) {
        const int oo = ty * 16 + i;
        bufB[tx][oo] = c1_w[oo * 64 + tx];   // c1T[k][o]
    }
    __syncthreads();

    if (t < 64) {    // softmax over q per k-row -> attnS in bufA[k][q]
        const int k = t;
        float m = -1e30f;
        for (int q = 0; q < 64; ++q) m = fmaxf(m, eT[q][k]);
        float s = 0.f;
        for (int q = 0; q < 64; ++q) {
            const float p = __expf(eT[q][k] - m);
            bufA[k][q] = p;
            s += p;
        }
        const float inv = 1.f / s;
        for (int q = 0; q < 64; ++q) bufA[k][q] *= inv;
    }
    __syncthreads();

    float acc[16];
    #pragma unroll
    for (int i = 0; i < 16; ++i) acc[i] = 0.f;
    #pragma unroll 4
    for (int k = 0; k < 64; ++k)
        FMA16(acc, bufA[k][tx], &bufB[k][ty * 16]);   // acc[i]: o=ty*16+i, q=tx
    #pragma unroll
    for (int i = 0; i < 16; ++i) {
        const int o = ty * 16 + i;
        const float s1 = c1_gamma[o] * rsqrtf(c1_var[o] + EPS_);
        M[((size_t)b * 64 + o) * 64 + tx] = s1 * acc[i];
    }
}

// ---------------------------------------------------------------------------
// T1: transpose-convert x -> actT[b][n][C8_+c] bf16. grid (64, 8, B), 256 thr.
// ---------------------------------------------------------------------------
__global__ __launch_bounds__(256) void k_xT(
        const float* __restrict__ x, unsigned short* __restrict__ actT) {
    __shared__ float S[64][65];
    const int t = threadIdx.x;
    const int tx = t & 63, ty = t >> 6;
    const int n0 = blockIdx.x * 64, c0 = blockIdx.y * 64, b = blockIdx.z;
    #pragma unroll
    for (int i = 0; i < 16; ++i) {
        const int r = ty * 16 + i;
        S[r][tx] = x[((size_t)(b * C_ + c0 + r)) * HW_ + n0 + tx];
    }
    __syncthreads();
    const int nl = t >> 2, seg = t & 3;
    unsigned short tmp[16];
    #pragma unroll
    for (int j = 0; j < 16; ++j) tmp[j] = f2bf(S[seg * 16 + j][nl]);
    unsigned short* dst = actT + ((size_t)(b * HW_ + n0 + nl)) * KW2_ + C8_ + c0 + seg * 16;
    *(bf16x8*)(dst)     = *(const bf16x8*)&tmp[0];
    *(bf16x8*)(dst + 8) = *(const bf16x8*)&tmp[8];
}

// ---------------------------------------------------------------------------
// T2: t[j,n] = relu(sum_q M[b,j,q]*att[b,q,n] + bias1[j]) -> actT[b][n][j] bf16
// grid (64, B), 256 thr.
// ---------------------------------------------------------------------------
__global__ __launch_bounds__(256) void k_t_bf(
        const float* __restrict__ att, const float* __restrict__ Mw,
        const float* __restrict__ c1_b, const float* __restrict__ c1_gamma,
        const float* __restrict__ c1_beta, const float* __restrict__ c1_mean,
        const float* __restrict__ c1_var, unsigned short* __restrict__ actT) {
    __shared__ __align__(16) float attS[64][65];
    __shared__ __align__(16) float MT[64][68];
    __shared__ float tS[64][65];
    const int t = threadIdx.x;
    const int tx = t & 63, ty = t >> 6;
    const int n0 = blockIdx.x * 64, b = blockIdx.y;

    #pragma unroll
    for (int i = 0; i < 16; ++i) {
        const int r = ty * 16 + i;
        attS[r][tx] = att[((size_t)b * C8_ + r) * HW_ + n0 + tx];
        MT[tx][r]   = Mw[((size_t)b * 64 + r) * 64 + tx];
    }
    __syncthreads();
    float acc[16];
    #pragma unroll
    for (int i = 0; i < 16; ++i) acc[i] = 0.f;
    #pragma unroll 4
    for (int q = 0; q < 64; ++q)
        FMA16(acc, attS[q][tx], &MT[q][ty * 16]);
    #pragma unroll
    for (int i = 0; i < 16; ++i) {
        const int j = ty * 16 + i;
        const float s1 = c1_gamma[j] * rsqrtf(c1_var[j] + EPS_);
        const float bias = s1 * c1_b[j] + c1_beta[j] - c1_mean[j] * s1;
        tS[j][tx] = fmaxf(acc[i] + bias, 0.f);
    }
    __syncthreads();
    const int nl = t >> 2, seg = t & 3;
    unsigned short tmp[16];
    #pragma unroll
    for (int j = 0; j < 16; ++j) tmp[j] = f2bf(tS[seg * 16 + j][nl]);
    unsigned short* dst = actT + ((size_t)(b * HW_ + n0 + nl)) * KW2_ + seg * 16;
    *(bf16x8*)(dst)     = *(const bf16x8*)&tmp[0];
    *(bf16x8*)(dst + 8) = *(const bf16x8*)&tmp[8];
}

// ---------------------------------------------------------------------------
// W: pre-convert weights: wbf[o][k] = bf16(c2_w[o][k] * s2[o]).
// grid (144), 256 thr; each thread one 8-elem segment (512*72 = 36864 segs).
// ---------------------------------------------------------------------------
__global__ __launch_bounds__(256) void k_wbf(
        const float* __restrict__ c2_w, const float* __restrict__ c2_gamma,
        const float* __restrict__ c2_var, unsigned short* __restrict__ wbf) {
    const int seg = blockIdx.x * 256 + threadIdx.x;   // < 36864
    const int o = seg / 72, ks = (seg % 72) * 8;
    const float s2 = c2_gamma[o] * rsqrtf(c2_var[o] + EPS_);
    const float4* src = (const float4*)(c2_w + (size_t)o * KW2_ + ks);
    float4 f0 = src[0], f1 = src[1];
    unsigned short tmp[8];
    tmp[0] = f2bf(f0.x * s2); tmp[1] = f2bf(f0.y * s2);
    tmp[2] = f2bf(f0.z * s2); tmp[3] = f2bf(f0.w * s2);
    tmp[4] = f2bf(f1.x * s2); tmp[5] = f2bf(f1.y * s2);
    tmp[6] = f2bf(f1.z * s2); tmp[7] = f2bf(f1.w * s2);
    *(bf16x8*)(wbf + (size_t)o * KW2_ + ks) = *(const bf16x8*)tmp;
}

// ---------------------------------------------------------------------------
// conv2 (wbf + T14 reg-prefetch): issue next K-tile's loads before the MFMA
// cluster; write them to LDS after the post-MFMA barrier. Load latency hides
// under compute. Block 128x128, 4 waves (2x2). grid (32, 4, B), 256 thr.
// ---------------------------------------------------------------------------
__global__ __launch_bounds__(256) void k_conv2_wbf(
        const unsigned short* __restrict__ actT, const unsigned short* __restrict__ wbf,
        const float* __restrict__ c2_b, const float* __restrict__ c2_gamma,
        const float* __restrict__ c2_beta, const float* __restrict__ c2_mean,
        const float* __restrict__ c2_var, float* __restrict__ out) {
    __shared__ __align__(16) unsigned short At[128 * 64];
    __shared__ __align__(16) unsigned short Bt[128 * 64];
    const int t = threadIdx.x;
    const int lane = t & 63, wave = t >> 6;
    const int wr = wave >> 1, wc = wave & 1;
    const int n0 = blockIdx.x * 128, o0 = blockIdx.y * 128, b = blockIdx.z;
    const int srow = t >> 1, shalf = t & 1;

    const unsigned short* srcA0 = wbf + (size_t)(o0 + srow) * KW2_ + shalf * 32;
    const unsigned short* srcB0 = actT + ((size_t)(b * HW_ + n0 + srow)) * KW2_ + shalf * 32;

    f32x4 acc[4][4];
    #pragma unroll
    for (int m = 0; m < 4; ++m)
        #pragma unroll
        for (int n = 0; n < 4; ++n) acc[m][n] = (f32x4){0.f, 0.f, 0.f, 0.f};

    // prologue: load + stage tile 0
    {
        bf16x8 ra[4], rb[4];
        #pragma unroll
        for (int v = 0; v < 4; ++v) {
            ra[v] = *(const bf16x8*)(srcA0 + v * 8);
            rb[v] = *(const bf16x8*)(srcB0 + v * 8);
        }
        #pragma unroll
        for (int v = 0; v < 4; ++v) {
            const int kb = shalf * 4 + v;
            *(bf16x8*)&At[srow * 64 + ((kb ^ (srow & 7)) << 3)] = ra[v];
            *(bf16x8*)&Bt[srow * 64 + ((kb ^ (srow & 7)) << 3)] = rb[v];
        }
    }
    __syncthreads();

    for (int ks = 0; ks < 9; ++ks) {
        // issue next tile's loads BEFORE the MFMA cluster (latency hides under it)
        bf16x8 na[4], nb[4];
        if (ks < 8) {
            const unsigned short* sA = srcA0 + (ks + 1) * 64;
            const unsigned short* sB = srcB0 + (ks + 1) * 64;
            #pragma unroll
            for (int v = 0; v < 4; ++v) {
                na[v] = *(const bf16x8*)(sA + v * 8);
                nb[v] = *(const bf16x8*)(sB + v * 8);
            }
        }
        // compute current tile from LDS
        #pragma unroll
        for (int kk = 0; kk < 2; ++kk) {
            const int g = lane >> 4, a7 = lane & 7, r15 = lane & 15;
            const int kb = kk * 4 + g;
            bf16x8 af[4], bfv[4];
            #pragma unroll
            for (int m = 0; m < 4; ++m) {
                const int row = wr * 64 + m * 16 + r15;
                af[m] = *(const bf16x8*)&At[row * 64 + ((kb ^ a7) << 3)];
            }
            #pragma unroll
            for (int n = 0; n < 4; ++n) {
                const int row = wc * 64 + n * 16 + r15;
                bfv[n] = *(const bf16x8*)&Bt[row * 64 + ((kb ^ a7) << 3)];
            }
            #pragma unroll
            for (int m = 0; m < 4; ++m)
                #pragma unroll
                for (int n = 0; n < 4; ++n)
                    acc[m][n] = __builtin_amdgcn_mfma_f32_16x16x32_bf16(
                        af[m], bfv[n], acc[m][n], 0, 0, 0);
        }
        __syncthreads();   // all waves done READING At/Bt
        if (ks < 8) {
            #pragma unroll
            for (int v = 0; v < 4; ++v) {
                const int kb = shalf * 4 + v;
                *(bf16x8*)&At[srow * 64 + ((kb ^ (srow & 7)) << 3)] = na[v];
                *(bf16x8*)&Bt[srow * 64 + ((kb ^ (srow & 7)) << 3)] = nb[v];
            }
            __syncthreads();   // next tile staged
        }
    }
    #pragma unroll
    for (int m = 0; m < 4; ++m) {
        #pragma unroll
        for (int r = 0; r < 4; ++r) {
            const int o = o0 + wr * 64 + m * 16 + (lane >> 4) * 4 + r;
            const float s2 = c2_gamma[o] * rsqrtf(c2_var[o] + EPS_);
            const float bias = s2 * (c2_b[o] - c2_mean[o]) + c2_beta[o];
            float* orow = out + ((size_t)(b * C_ + o)) * HW_ + n0 + wc * 64 + (lane & 15);
            #pragma unroll
            for (int n = 0; n < 4; ++n)
                orow[n * 16] = fmaxf(acc[m][n][r] + bias, 0.f);
        }
    }
}

// ---------------------------------------------------------------------------
// conv2 (legacy, fp32 weights staged in-kernel) — mid ws path.
// ---------------------------------------------------------------------------
__global__ __launch_bounds__(256) void k_conv2_mfma(
        const unsigned short* __restrict__ actT, const float* __restrict__ c2_w,
        const float* __restrict__ c2_b, const float* __restrict__ c2_gamma,
        const float* __restrict__ c2_beta, const float* __restrict__ c2_mean,
        const float* __restrict__ c2_var, float* __restrict__ out) {
    __shared__ __align__(16) unsigned short At[128 * 64];
    __shared__ __align__(16) unsigned short Bt[128 * 64];
    const int t = threadIdx.x;
    const int lane = t & 63, wave = t >> 6;
    const int wr = wave >> 1, wc = wave & 1;
    const int n0 = blockIdx.x * 128, o0 = blockIdx.y * 128, b = blockIdx.z;
    const int srow = t >> 1, shalf = t & 1;
    const int oA = o0 + srow;
    const float s2A = c2_gamma[oA] * rsqrtf(c2_var[oA] + EPS_);

    f32x4 acc[4][4];
    #pragma unroll
    for (int m = 0; m < 4; ++m)
        #pragma unroll
        for (int n = 0; n < 4; ++n) acc[m][n] = (f32x4){0.f, 0.f, 0.f, 0.f};

    for (int ks = 0; ks < 9; ++ks) {
        const int k0 = ks * 64;
        {
            const float4* src = (const float4*)(c2_w + (size_t)oA * KW2_ + k0 + shalf * 32);
            unsigned short tmp[32];
            #pragma unroll
            for (int v = 0; v < 8; ++v) {
                float4 f = src[v];
                tmp[v * 4 + 0] = f2bf(f.x * s2A);
                tmp[v * 4 + 1] = f2bf(f.y * s2A);
                tmp[v * 4 + 2] = f2bf(f.z * s2A);
                tmp[v * 4 + 3] = f2bf(f.w * s2A);
            }
            #pragma unroll
            for (int v = 0; v < 4; ++v) {
                const int kb = shalf * 4 + v;
                *(bf16x8*)&At[srow * 64 + ((kb ^ (srow & 7)) << 3)] =
                    *(const bf16x8*)&tmp[v * 8];
            }
        }
        {
            const unsigned short* src =
                actT + ((size_t)(b * HW_ + n0 + srow)) * KW2_ + k0 + shalf * 32;
            #pragma unroll
            for (int v = 0; v < 4; ++v) {
                const int kb = shalf * 4 + v;
                *(bf16x8*)&Bt[srow * 64 + ((kb ^ (srow & 7)) << 3)] =
                    *(const bf16x8*)(src + v * 8);
            }
        }
        __syncthreads();
        #pragma unroll
        for (int kk = 0; kk < 2; ++kk) {
            const int g = lane >> 4, a7 = lane & 7, r15 = lane & 15;
            const int kb = kk * 4 + g;
            bf16x8 af[4], bfv[4];
            #pragma unroll
            for (int m = 0; m < 4; ++m) {
                const int row = wr * 64 + m * 16 + r15;
                af[m] = *(const bf16x8*)&At[row * 64 + ((kb ^ a7) << 3)];
            }
            #pragma unroll
            for (int n = 0; n < 4; ++n) {
                const int row = wc * 64 + n * 16 + r15;
                bfv[n] = *(const bf16x8*)&Bt[row * 64 + ((kb ^ a7) << 3)];
            }
            #pragma unroll
            for (int m = 0; m < 4; ++m)
                #pragma unroll
                for (int n = 0; n < 4; ++n)
                    acc[m][n] = __builtin_amdgcn_mfma_f32_16x16x32_bf16(
                        af[m], bfv[n], acc[m][n], 0, 0, 0);
        }
        __syncthreads();
    }
    #pragma unroll
    for (int m = 0; m < 4; ++m) {
        #pragma unroll
        for (int r = 0; r < 4; ++r) {
            const int o = o0 + wr * 64 + m * 16 + (lane >> 4) * 4 + r;
            const float s2 = c2_gamma[o] * rsqrtf(c2_var[o] + EPS_);
            const float bias = s2 * (c2_b[o] - c2_mean[o]) + c2_beta[o];
            float* orow = out + ((size_t)(b * C_ + o)) * HW_ + n0 + wc * 64 + (lane & 15);
            #pragma unroll
            for (int n = 0; n < 4; ++n)
                orow[n * 16] = fmaxf(acc[m][n][r] + bias, 0.f);
        }
    }
}

// ---------------------------------------------------------------------------
// Fallback (fp32 VALU) conv2 path, used only if ws too small for actT.
// ---------------------------------------------------------------------------
__global__ __launch_bounds__(256) void k_fused_out(
        const float* __restrict__ att, const float* __restrict__ Mw,
        const float* __restrict__ c1_b, const float* __restrict__ c1_gamma,
        const float* __restrict__ c1_beta, const float* __restrict__ c1_mean,
        const float* __restrict__ c1_var,
        const float* __restrict__ x, const float* __restrict__ c2_w,
        const float* __restrict__ c2_b, const float* __restrict__ c2_gamma,
        const float* __restrict__ c2_beta, const float* __restrict__ c2_mean,
        const float* __restrict__ c2_var, float* __restrict__ out) {
    __shared__ __align__(16) float sA[64][65];
    __shared__ __align__(16) float sW[64][68];
    __shared__ __align__(16) float tS[64][65];
    const int tx = threadIdx.x, ty = threadIdx.y;
    const int n0 = blockIdx.x * 64, o0 = blockIdx.y * 64, b = blockIdx.z;

    #pragma unroll
    for (int i = 0; i < 16; ++i) {
        const int r = ty * 16 + i;
        sA[r][tx] = att[((size_t)b * C8_ + r) * HW_ + n0 + tx];
        sW[tx][r] = Mw[((size_t)b * 64 + r) * 64 + tx];
    }
    __syncthreads();
    float acc[16];
    #pragma unroll
    for (int i = 0; i < 16; ++i) acc[i] = 0.f;
    #pragma unroll 4
    for (int q = 0; q < 64; ++q)
        FMA16(acc, sA[q][tx], &sW[q][ty * 16]);
    #pragma unroll
    for (int i = 0; i < 16; ++i) {
        const int j = ty * 16 + i;
        const float s1 = c1_gamma[j] * rsqrtf(c1_var[j] + EPS_);
        const float bias = s1 * c1_b[j] + c1_beta[j] - c1_mean[j] * s1;
        tS[j][tx] = fmaxf(acc[i] + bias, 0.f);
    }
    __syncthreads();

    #pragma unroll
    for (int i = 0; i < 16; ++i) acc[i] = 0.f;
    for (int cch = 0; cch < 9; ++cch) {
        #pragma unroll
        for (int i = 0; i < 16; ++i) {
            const int r = ty * 16 + i;
            sW[tx][r] = c2_w[(size_t)(o0 + r) * KW2_ + cch * 64 + tx];
            if (cch > 0)
                sA[r][tx] = x[((size_t)b * C_ + (cch - 1) * 64 + r) * HW_ + n0 + tx];
        }
        __syncthreads();
        const float (*src)[65] = (cch == 0) ? tS : sA;
        #pragma unroll 4
        for (int jj = 0; jj < 64; ++jj)
            FMA16(acc, src[jj][tx], &sW[jj][ty * 16]);
        __syncthreads();
    }
    #pragma unroll
    for (int i = 0; i < 16; ++i) {
        const int o = o0 + ty * 16 + i;
        const float s2 = c2_gamma[o] * rsqrtf(c2_var[o] + EPS_);
        const float v = (acc[i] + c2_b[o]) * s2 + c2_beta[o] - c2_mean[o] * s2;
        out[((size_t)b * C_ + o) * HW_ + n0 + tx] = fmaxf(v, 0.f);
    }
}

extern "C" void kernel_launch(void* const* d_in, const int* in_sizes, int n_in,
                              void* d_out, int out_size, void* d_ws, size_t ws_size,
                              hipStream_t stream) {
    const float* x        = (const float*)d_in[0];
    const float* att      = (const float*)d_in[1];
    const float* key_w    = (const float*)d_in[2];
    const float* key_b    = (const float*)d_in[3];
    const float* c1_w     = (const float*)d_in[4];
    const float* c1_b     = (const float*)d_in[5];
    const float* c1_gamma = (const float*)d_in[6];
    const float* c1_beta  = (const float*)d_in[7];
    const float* c1_mean  = (const float*)d_in[8];
    const float* c1_var   = (const float*)d_in[9];
    const float* c2_w     = (const float*)d_in[10];
    const float* c2_b     = (const float*)d_in[11];
    const float* c2_gamma = (const float*)d_in[12];
    const float* c2_beta  = (const float*)d_in[13];
    const float* c2_mean  = (const float*)d_in[14];
    const float* c2_var   = (const float*)d_in[15];
    float* out = (float*)d_out;

    // ws: M (256KB) | actT (75.5MB) | wbf (590KB) | S (4KB)
    const size_t off_actT = 262144;
    const size_t off_wbf  = off_actT + (size_t)B_ * HW_ * KW2_ * 2;
    const size_t off_S    = off_wbf + (size_t)C_ * KW2_ * 2;
    const size_t ws_full  = off_S + (size_t)B_ * C8_ * 4;
    const size_t ws_mid   = off_wbf;

    float* M = (float*)d_ws;
    unsigned short* actT = (unsigned short*)((char*)d_ws + off_actT);
    unsigned short* wbf  = (unsigned short*)((char*)d_ws + off_wbf);
    float* Sbuf          = (float*)((char*)d_ws + off_S);

    // epart (16.8MB) + G (2.1MB) borrow d_out's head; both fully consumed by
    // k_energy_softmax_M before any kernel writes out (stream-ordered).
    float* epart = out;
    float* Gbuf  = out + (size_t)B_ * 8 * 512 * 64;

    k_G      <<<dim3(8, 4, B_), 256, 0, stream>>>(x, att, epart);
    k_reduceG<<<dim3(32, B_),   256, 0, stream>>>(epart, Gbuf);

    if (ws_size >= ws_full) {
        k_S<<<dim3(C8_, B_), 256, 0, stream>>>(att, Sbuf);
        k_energy_softmax_M<<<dim3(B_), dim3(64, 4), 0, stream>>>(
            Gbuf, att, key_w, key_b, c1_w, c1_gamma, c1_var, Sbuf, M);
        k_xT  <<<dim3(64, 8, B_), 256, 0, stream>>>(x, actT);
        k_t_bf<<<dim3(64, B_),    256, 0, stream>>>(
            att, M, c1_b, c1_gamma, c1_beta, c1_mean, c1_var, actT);
        k_wbf <<<dim3(144),       256, 0, stream>>>(c2_w, c2_gamma, c2_var, wbf);
        k_conv2_wbf<<<dim3(32, 4, B_), 256, 0, stream>>>(
            actT, wbf, c2_b, c2_gamma, c2_beta, c2_mean, c2_var, out);
    } else if (ws_size >= ws_mid) {
        k_energy_softmax_M<<<dim3(B_), dim3(64, 4), 0, stream>>>(
            Gbuf, att, key_w, key_b, c1_w, c1_gamma, c1_var, nullptr, M);
        k_xT  <<<dim3(64, 8, B_), 256, 0, stream>>>(x, actT);
        k_t_bf<<<dim3(64, B_),    256, 0, stream>>>(
            att, M, c1_b, c1_gamma, c1_beta, c1_mean, c1_var, actT);
        k_conv2_mfma<<<dim3(32, 4, B_), 256, 0, stream>>>(
            actT, c2_w, c2_b, c2_gamma, c2_beta, c2_mean, c2_var, out);
    } else {
        k_energy_softmax_M<<<dim3(B_), dim3(64, 4), 0, stream>>>(
            Gbuf, att, key_w, key_b, c1_w, c1_gamma, c1_var, nullptr, M);
        k_fused_out<<<dim3(HW_ / 64, C_ / 64, B_), dim3(64, 4), 0, stream>>>(
            att, M, c1_b, c1_gamma, c1_beta, c1_mean, c1_var,
            x, c2_w, c2_b, c2_gamma, c2_beta, c2_mean, c2_var, out);
    }
}